// Round 10
// baseline (305.278 us; speedup 1.0000x reference)
//
#include <hip/hip_runtime.h>
#include <math.h>

// FactorizedSpectralConv2d: pruned-DFT + TT contraction, MFMA everywhere matmul-shaped.
//
//   k_prepT    : split-bf16 MFMA A-frag tables for FH / IH DFT matrices + B-frag table for FW
//   k_g        : g[r][j][x][y] = sum_k cc[j,x,k]*dc[k,y]
//   k_stage1m  : W-DFT of x via split-bf16 MFMA -> Yt 4 bf16 planes [h/8][p][8]
//                (1 mtile/wave, per-nt B-frags, x prefetch: occupancy-tuned)
//   k_cmfma    : XF[k][p] = sum_h FH[k][h] Yt[h][p]    (split-bf16 complex MFMA)
//   k_prepBG   : bf16 frag tables for b (A) and g (B) of the TT contraction
//   k_prepA    : split-bf16 A-frag table for the a (Cout x r1) epilogue GEMM (over dead G)
//   k_contractA: MFMA w-GEMM + fp32 t-update; t written as split-bf16 frag planes tA
//   k_amfma    : OF[o,(k,b,m)] = sum_i a[o,i] tA[i,(k,b,m)]   (split-bf16 MFMA)
//   k_repack   : OF fp32 -> OFt 4 bf16 planes [k/8][p][8]
//   k_prepE    : bf16 B-frag table for the inverse-W twiddle (into dead OF region)
//   k_cmfma    : Z[h][q] = sum_k IH[h][k] OFt[k][q]
//   k_invWm    : out[(b,o,h)][w] = Re(Z . E) via MFMA (Z split hi/lo on the fly)

#define TWO_PI 6.28318530717958647692f

typedef __attribute__((ext_vector_type(8))) short short8v;   // 8 bf16 (4 VGPRs)
typedef __attribute__((ext_vector_type(4))) float float4v;   // MFMA C/D

namespace {
constexpr size_t P_ = 32768;            // B*C*KW pixel batch width

// workspace float offsets
constexpr size_t oYT = 0;                     // Yt: 4 planes [32][32768][8] bf16 = 16.77M floats
                                              //   then bA/gB + tA (contract), then Z f2
constexpr size_t oTA = 1048576;               // tA: 4 planes [8][32768][8] bf16
constexpr size_t oXF = 16777216;              // XF f2 33.5MB; later OFt 4 planes [16][32768][8]
constexpr size_t oOF = 25165824;              // OF f2 33.5MB; later EF (invW twiddle frags)
constexpr size_t oBF = 33554432;              // FW B-frag table: 65536 shorts
constexpr size_t oAF1 = 33587200;             // FH frags: 196608 shorts
constexpr size_t oAF2 = 33685504;             // IH frags
constexpr size_t oG  = 33792000;              // [2][32][64][64] f2 ; AFa overwrites after prepBG
constexpr size_t WS_FLOATS = oG + 524288;     // ~137.3 MB
}

__device__ __forceinline__ unsigned short f2bf(float f) {   // RNE float->bf16 bits
    unsigned int u = __float_as_uint(f);
    unsigned int r = (u + 0x7FFFu + ((u >> 16) & 1u)) >> 16;
    return (unsigned short)r;
}
__device__ __forceinline__ float bf2f(unsigned short b) {
    return __uint_as_float(((unsigned int)b) << 16);
}

// Split-bf16 fragment tables for the DFT matrices (AF1 FH, AF2 IH, BF FW).
__global__ __launch_bounds__(256) void k_prepT(unsigned short* __restrict__ AF1,
                                               unsigned short* __restrict__ AF2,
                                               unsigned short* __restrict__ BF) {
    int idx = blockIdx.x * 256 + threadIdx.x;      // < 458752
    if (idx < 393216) {
        int tbl = (idx >= 196608);
        int id = tbl ? (idx - 196608) : idx;
        int e = id & 7, lane = (id >> 3) & 63;
        int pl = id >> 15;
        float ang;
        if (!tbl) {
            int rt = (id >> 9) & 7, kc = (id >> 12) & 7;
            int r = rt * 16 + (lane & 15);             // k-row (128)
            int s = kc * 32 + 8 * (lane >> 4) + e;     // h (256)
            int kh = r + ((r >= 64) ? 128 : 0);
            int ph = (kh * s) & 255;
            ang = -TWO_PI * (float)ph / 256.0f;
        } else {
            int rt = (id >> 9) & 15, kc = (id >> 13) & 3;
            int r = rt * 16 + (lane & 15);             // h (256)
            int s = kc * 32 + 8 * (lane >> 4) + e;     // k (128)
            int kh = s + ((s >= 64) ? 128 : 0);
            int ph = (kh * r) & 255;
            ang = TWO_PI * (float)ph / 256.0f;
        }
        float sn, cs; sincosf(ang, &sn, &cs);
        float base = (pl < 2) ? cs : ((pl < 4) ? sn : -sn);
        unsigned short hi = f2bf(base);
        unsigned short out = (pl & 1) ? f2bf(base - bf2f(hi)) : hi;
        (tbl ? AF2 : AF1)[id] = out;
    } else {
        int id = idx - 393216;                          // < 65536
        int e = id & 7, lane = (id >> 3) & 63;
        int nt = (id >> 9) & 3, kc = (id >> 11) & 7;
        int pl = id >> 14;                              // 0..3
        int kw = nt * 16 + (lane & 15);
        int w = kc * 32 + 8 * (lane >> 4) + e;
        int ph = (w * kw) & 255;
        float ang = -TWO_PI * (float)ph / 256.0f;
        float sn, cs; sincosf(ang, &sn, &cs);
        float base = (pl < 2) ? cs : sn;
        unsigned short hi = f2bf(base);
        unsigned short out = (pl & 1) ? f2bf(base - bf2f(hi)) : hi;
        BF[id] = out;
    }
}

// bf16-hi B-frag table for the inverse-W twiddle:
// EF[pl(2: Er, -Ei)][kc(2)][nt(16)][lane][e], E[kw][w] = s_kw/65536 * e^{+2pi i kw w/256}
__global__ __launch_bounds__(256) void k_prepE(unsigned short* __restrict__ EF) {
    int idx = blockIdx.x * 256 + threadIdx.x;      // < 32768
    int e = idx & 7, lane = (idx >> 3) & 63;
    int nt = (idx >> 9) & 15, kc = (idx >> 13) & 1, pl = idx >> 14;
    int w = nt * 16 + (lane & 15);
    int kw = kc * 32 + 8 * (lane >> 4) + e;
    int ph = (kw * w) & 255;
    float ang = TWO_PI * (float)ph / 256.0f;
    float sn, cs; sincosf(ang, &sn, &cs);
    float sc = ((kw == 0) ? 1.0f : 2.0f) / 65536.0f;
    float v = (pl == 0) ? (sc * cs) : (-sc * sn);
    EF[idx] = f2bf(v);
}

// g[r][j][x][y] = sum_k cc[j,x,k] * dc[k,y]
__global__ __launch_bounds__(256) void k_g(const float* __restrict__ c1, const float* __restrict__ d1,
                                           const float* __restrict__ c2, const float* __restrict__ d2,
                                           float2* __restrict__ G) {
    int idx = blockIdx.x * 256 + threadIdx.x;      // < 262144
    int r = idx >> 17;
    int rem = idx & 131071;
    int j = rem >> 12;
    int xy = rem & 4095;
    int xm = xy >> 6, ym = xy & 63;
    const float* cp = r ? c2 : c1;
    const float* dp = r ? d2 : d1;
    float sr = 0.f, si = 0.f;
    for (int kk = 0; kk < 32; ++kk) {
        float cr = cp[((j * 64 + xm) * 32 + kk) * 2 + 0];
        float ci = cp[((j * 64 + xm) * 32 + kk) * 2 + 1];
        float dr = dp[(kk * 64 + ym) * 2 + 0];
        float di = dp[(kk * 64 + ym) * 2 + 1];
        sr = fmaf(cr, dr, fmaf(-ci, di, sr));
        si = fmaf(cr, di, fmaf( ci, dr, si));
    }
    G[(size_t)(r * 32 + j) * 4096 + xy] = make_float2(sr, si);
}

// bf16 fragment tables for the contraction.
__global__ __launch_bounds__(256) void k_prepBG(const float* __restrict__ b1, const float* __restrict__ b2,
                                                const float2* __restrict__ G,
                                                unsigned short* __restrict__ bA,
                                                unsigned short* __restrict__ gB) {
    size_t idx = (size_t)blockIdx.x * 256 + threadIdx.x;
    if (idx < 1048576) {
        int e     = idx & 7;
        int lane  = (idx >> 3) & 63;
        int c     = (idx >> 9) & 127;
        int itile = (idx >> 16) & 3;
        int reg   = (idx >> 18) & 1;
        int plane = (idx >> 19) & 1;
        int i = itile * 16 + (lane & 15);
        int j = 8 * (lane >> 4) + e;
        const float* bp = reg ? b2 : b1;
        float v = bp[((size_t)(i * 128 + c) * 32 + j) * 2 + plane];
        bA[idx] = f2bf(v);
    } else if (idx < 1048576 + 786432) {
        size_t i2 = idx - 1048576;
        int e     = i2 & 7;
        int lane  = (i2 >> 3) & 63;
        int ytile = (i2 >> 9) & 3;
        int x     = (i2 >> 11) & 63;
        int reg   = (i2 >> 17) & 1;
        int plane = (int)(i2 >> 18);           // 0,1,2
        int y = ytile * 16 + (lane & 15);
        int j = 8 * (lane >> 4) + e;
        float2 gv = G[(size_t)(reg * 32 + j) * 4096 + x * 64 + y];
        float v = (plane == 0) ? gv.x : ((plane == 1) ? gv.y : -gv.y);
        gB[i2] = f2bf(v);
    }
}

// Split-bf16 A-frag table for the a-epilogue GEMM (M=o=128, K=i=64).
__global__ __launch_bounds__(256) void k_prepA(const float* __restrict__ a1, const float* __restrict__ a2,
                                               unsigned short* __restrict__ AFa) {
    int idx = blockIdx.x * 256 + threadIdx.x;      // < 98304
    int e = idx & 7, lane = (idx >> 3) & 63;
    int rt = (idx >> 9) & 7, kc = (idx >> 12) & 1;
    int plreg = idx >> 13;                          // 0..11
    int reg = plreg / 6, pl = plreg % 6;
    int o = rt * 16 + (lane & 15);
    int i = kc * 32 + 8 * (lane >> 4) + e;
    const float* ap = reg ? a2 : a1;
    float ar = ap[(o * 64 + i) * 2 + 0];
    float ai = ap[(o * 64 + i) * 2 + 1];
    float base = (pl < 2) ? ar : ((pl < 4) ? ai : -ai);
    unsigned short hi = f2bf(base);
    unsigned short out = (pl & 1) ? f2bf(base - bf2f(hi)) : hi;
    AFa[idx] = out;
}

// MFMA W-DFT v2: wave = ONE 16-row mtile (64 rows/block, grid 2048); per-nt B-frag
// loads (transient regs); x prefetched one kc ahead. K=256 (w), split-bf16.
__global__ __launch_bounds__(256) void k_stage1m(const float* __restrict__ x,
                                                 const unsigned short* __restrict__ BF,
                                                 unsigned short* __restrict__ Yt) {
    int t = threadIdx.x;
    int wave = t >> 6, lane = t & 63;
    size_t row0 = (size_t)blockIdx.x * 64 + (size_t)wave * 16;
    int colp = lane & 15, rowq = lane >> 4;
    const short8v* BFv = (const short8v*)BF;
    const size_t PLB = 8 * 4 * 64;

    float4v accR[4], accI[4];
#pragma unroll
    for (int nt = 0; nt < 4; ++nt) {
        accR[nt] = (float4v){0.f, 0.f, 0.f, 0.f};
        accI[nt] = (float4v){0.f, 0.f, 0.f, 0.f};
    }

    const float* xbase = x + (row0 + colp) * 256 + 8 * rowq;
    float4 nv0 = *(const float4*)(xbase);
    float4 nv1 = *(const float4*)(xbase + 4);

    for (int kc = 0; kc < 8; ++kc) {
        float4 v0 = nv0, v1 = nv1;
        if (kc < 7) {                         // prefetch next chunk under this chunk's MFMAs
            nv0 = *(const float4*)(xbase + (kc + 1) * 32);
            nv1 = *(const float4*)(xbase + (kc + 1) * 32 + 4);
        }
        float vv[8] = {v0.x, v0.y, v0.z, v0.w, v1.x, v1.y, v1.z, v1.w};
        short8v xh, xl;
#pragma unroll
        for (int j = 0; j < 8; ++j) {
            unsigned short h = f2bf(vv[j]);
            xh[j] = (short)h;
            xl[j] = (short)f2bf(vv[j] - bf2f(h));
        }
#pragma unroll
        for (int nt = 0; nt < 4; ++nt) {
            size_t bb = ((size_t)kc * 4 + nt) * 64 + lane;
            short8v Bch = BFv[0 * PLB + bb];
            short8v Bcl = BFv[1 * PLB + bb];
            short8v Bsh = BFv[2 * PLB + bb];
            short8v Bsl = BFv[3 * PLB + bb];
            float4v r_ = accR[nt];
            r_ = __builtin_amdgcn_mfma_f32_16x16x32_bf16(xh, Bch, r_, 0, 0, 0);
            r_ = __builtin_amdgcn_mfma_f32_16x16x32_bf16(xh, Bcl, r_, 0, 0, 0);
            r_ = __builtin_amdgcn_mfma_f32_16x16x32_bf16(xl, Bch, r_, 0, 0, 0);
            accR[nt] = r_;
            float4v i_ = accI[nt];
            i_ = __builtin_amdgcn_mfma_f32_16x16x32_bf16(xh, Bsh, i_, 0, 0, 0);
            i_ = __builtin_amdgcn_mfma_f32_16x16x32_bf16(xh, Bsl, i_, 0, 0, 0);
            i_ = __builtin_amdgcn_mfma_f32_16x16x32_bf16(xl, Bsh, i_, 0, 0, 0);
            accI[nt] = i_;
        }
    }

    // write split-bf16 Yt: D row=(lane>>4)*4+q -> x-row, col=lane&15 -> kw
    short* Yts = (short*)Yt;
    const size_t PLY = (size_t)32 * 32768 * 8;
    size_t xrow0 = row0 + rowq * 4;
    int h = (int)(xrow0 & 255), bc = (int)(xrow0 >> 8);
    size_t gbase = (size_t)(h >> 3) * 32768;
    int e0 = h & 7;                                   // 0 or 4
#pragma unroll
    for (int nt = 0; nt < 4; ++nt) {
        size_t p = (size_t)bc * 64 + nt * 16 + colp;
        size_t off = (gbase + p) * 8 + e0;
        float4v R = accR[nt], I = accI[nt];
        short rh[4], rl[4], ih[4], il[4];
#pragma unroll
        for (int q = 0; q < 4; ++q) {
            unsigned short h1 = f2bf(R[q]);
            rh[q] = (short)h1; rl[q] = (short)f2bf(R[q] - bf2f(h1));
            unsigned short h2 = f2bf(I[q]);
            ih[q] = (short)h2; il[q] = (short)f2bf(I[q] - bf2f(h2));
        }
        *(short4*)&Yts[0 * PLY + off] = make_short4(rh[0], rh[1], rh[2], rh[3]);
        *(short4*)&Yts[1 * PLY + off] = make_short4(rl[0], rl[1], rl[2], rl[3]);
        *(short4*)&Yts[2 * PLY + off] = make_short4(ih[0], ih[1], ih[2], ih[3]);
        *(short4*)&Yts[3 * PLY + off] = make_short4(il[0], il[1], il[2], il[3]);
    }
}

// Split-bf16 complex MFMA GEMM: Out[r][p] = sum_s T[r][s] * D[s][p].
template<int S, int RT_W>
__global__ __launch_bounds__(256) void k_cmfma(const unsigned short* __restrict__ AF,
                                               const unsigned short* __restrict__ Bt,
                                               float2* __restrict__ Out) {
    constexpr int KC = S / 32;
    constexpr int SG = S / 8;
    constexpr int RTOT = RT_W * 4;
    __shared__ __align__(16) unsigned short bs[4 * SG * 16 * 8];
    int t = threadIdx.x;
    int wave = t >> 6, lane = t & 63;
    int rt0 = wave * RT_W;
    int colp = lane & 15, rowq = lane >> 4;
    const short8v* AFv = (const short8v*)AF;
    const short8v* bsv = (const short8v*)bs;
    const size_t PLA = (size_t)KC * RTOT * 64;

    for (int pt = 0; pt < 4; ++pt) {
        int p0 = blockIdx.x * 64 + pt * 16;
        __syncthreads();
        {
            const float4* src = (const float4*)Bt;
            float4* dst = (float4*)bs;
            for (int e = t; e < 4 * SG * 16; e += 256) {
                int pl = e / (SG * 16); int rem = e - pl * (SG * 16);
                int g = rem >> 4, li = rem & 15;
                dst[e] = src[((size_t)pl * SG + g) * 32768 + p0 + li];
            }
        }
        __syncthreads();
        float4v accR[RT_W], accI[RT_W];
#pragma unroll
        for (int rt = 0; rt < RT_W; ++rt) {
            accR[rt] = (float4v){0.f, 0.f, 0.f, 0.f};
            accI[rt] = (float4v){0.f, 0.f, 0.f, 0.f};
        }
#pragma unroll
        for (int kc = 0; kc < KC; ++kc) {
            int gi = kc * 4 + rowq;
            short8v Brh = bsv[((0 * SG + gi) << 4) + colp];
            short8v Brl = bsv[((1 * SG + gi) << 4) + colp];
            short8v Bih = bsv[((2 * SG + gi) << 4) + colp];
            short8v Bil = bsv[((3 * SG + gi) << 4) + colp];
#pragma unroll
            for (int rt = 0; rt < RT_W; ++rt) {
                size_t ab = ((size_t)kc * RTOT + rt0 + rt) * 64 + lane;
                short8v A0 = AFv[0 * PLA + ab];
                short8v A1 = AFv[1 * PLA + ab];
                short8v A2 = AFv[2 * PLA + ab];
                short8v A3 = AFv[3 * PLA + ab];
                short8v A4 = AFv[4 * PLA + ab];
                short8v A5 = AFv[5 * PLA + ab];
                float4v r_ = accR[rt];
                r_ = __builtin_amdgcn_mfma_f32_16x16x32_bf16(A0, Brh, r_, 0, 0, 0);
                r_ = __builtin_amdgcn_mfma_f32_16x16x32_bf16(A0, Brl, r_, 0, 0, 0);
                r_ = __builtin_amdgcn_mfma_f32_16x16x32_bf16(A1, Brh, r_, 0, 0, 0);
                r_ = __builtin_amdgcn_mfma_f32_16x16x32_bf16(A4, Bih, r_, 0, 0, 0);
                r_ = __builtin_amdgcn_mfma_f32_16x16x32_bf16(A4, Bil, r_, 0, 0, 0);
                r_ = __builtin_amdgcn_mfma_f32_16x16x32_bf16(A5, Bih, r_, 0, 0, 0);
                accR[rt] = r_;
                float4v i_ = accI[rt];
                i_ = __builtin_amdgcn_mfma_f32_16x16x32_bf16(A2, Brh, i_, 0, 0, 0);
                i_ = __builtin_amdgcn_mfma_f32_16x16x32_bf16(A2, Brl, i_, 0, 0, 0);
                i_ = __builtin_amdgcn_mfma_f32_16x16x32_bf16(A3, Brh, i_, 0, 0, 0);
                i_ = __builtin_amdgcn_mfma_f32_16x16x32_bf16(A0, Bih, i_, 0, 0, 0);
                i_ = __builtin_amdgcn_mfma_f32_16x16x32_bf16(A0, Bil, i_, 0, 0, 0);
                i_ = __builtin_amdgcn_mfma_f32_16x16x32_bf16(A1, Bih, i_, 0, 0, 0);
                accI[rt] = i_;
            }
        }
#pragma unroll
        for (int rt = 0; rt < RT_W; ++rt) {
            int rbase = (rt0 + rt) * 16 + rowq * 4;
#pragma unroll
            for (int q = 0; q < 4; ++q)
                Out[(size_t)(rbase + q) * P_ + p0 + colp] = make_float2(accR[rt][q], accI[rt][q]);
        }
    }
}

// MFMA contract, phase A.
__global__ __launch_bounds__(256) void k_contractA(const float2* __restrict__ XF,
                                                   const unsigned short* __restrict__ bA,
                                                   const unsigned short* __restrict__ gB,
                                                   unsigned short* __restrict__ tA) {
    int t = threadIdx.x;
    int k = blockIdx.x >> 2;
    int ytile = blockIdx.x & 3;
    int y0 = ytile << 4;
    int reg = (k >= 64) ? 1 : 0;
    int x = k & 63;
    int itile = t >> 6, lane = t & 63;
    int ylane = lane & 15, qg = lane >> 4;

    const short8v* gBv = (const short8v*)gB;
    short8v g_r  = gBv[(((size_t)(0 * 2 + reg) * 64 + x) * 4 + ytile) * 64 + lane];
    short8v g_i  = gBv[(((size_t)(1 * 2 + reg) * 64 + x) * 4 + ytile) * 64 + lane];
    short8v g_ni = gBv[(((size_t)(2 * 2 + reg) * 64 + x) * 4 + ytile) * 64 + lane];

    const short8v* bAv = (const short8v*)bA;
    size_t aR = (((size_t)(0 * 2 + reg) * 4 + itile) * 128) * 64 + lane;
    size_t aI = (((size_t)(1 * 2 + reg) * 4 + itile) * 128) * 64 + lane;

    const float2* xfp = XF + (size_t)k * 32768 + y0 + ylane;

    float tr[4][4], ti[4][4];
#pragma unroll
    for (int q = 0; q < 4; ++q)
#pragma unroll
        for (int b = 0; b < 4; ++b) { tr[q][b] = 0.f; ti[q][b] = 0.f; }

#pragma unroll 2
    for (int c = 0; c < 128; ++c) {
        short8v av = bAv[aR + (size_t)c * 64];
        short8v aw = bAv[aI + (size_t)c * 64];
        float4v z4 = {0.f, 0.f, 0.f, 0.f};
        float4v wr = __builtin_amdgcn_mfma_f32_16x16x32_bf16(av, g_r, z4, 0, 0, 0);
        wr = __builtin_amdgcn_mfma_f32_16x16x32_bf16(aw, g_ni, wr, 0, 0, 0);
        float4v wi = __builtin_amdgcn_mfma_f32_16x16x32_bf16(av, g_i, z4, 0, 0, 0);
        wi = __builtin_amdgcn_mfma_f32_16x16x32_bf16(aw, g_r, wi, 0, 0, 0);
#pragma unroll
        for (int b = 0; b < 4; ++b) {
            float2 xv = xfp[(size_t)b * 8192 + (size_t)c * 64];
#pragma unroll
            for (int q = 0; q < 4; ++q) {
                tr[q][b] = fmaf(wr[q], xv.x, fmaf(-wi[q], xv.y, tr[q][b]));
                ti[q][b] = fmaf(wr[q], xv.y, fmaf( wi[q], xv.x, ti[q][b]));
            }
        }
    }

    short* tAs = (short*)tA;
    const size_t PLT = (size_t)8 * 32768 * 8;
    int gidx = itile * 2 + (qg >> 1);
    int e0 = (qg & 1) * 4;
#pragma unroll
    for (int b = 0; b < 4; ++b) {
        size_t col = (size_t)k * 256 + (size_t)b * 64 + y0 + ylane;
        size_t off = ((size_t)gidx * 32768 + col) * 8 + e0;
        short rh[4], rl[4], ih[4], il[4];
#pragma unroll
        for (int q = 0; q < 4; ++q) {
            unsigned short h1 = f2bf(tr[q][b]);
            rh[q] = (short)h1; rl[q] = (short)f2bf(tr[q][b] - bf2f(h1));
            unsigned short h2 = f2bf(ti[q][b]);
            ih[q] = (short)h2; il[q] = (short)f2bf(ti[q][b] - bf2f(h2));
        }
        *(short4*)&tAs[0 * PLT + off] = make_short4(rh[0], rh[1], rh[2], rh[3]);
        *(short4*)&tAs[1 * PLT + off] = make_short4(rl[0], rl[1], rl[2], rl[3]);
        *(short4*)&tAs[2 * PLT + off] = make_short4(ih[0], ih[1], ih[2], ih[3]);
        *(short4*)&tAs[3 * PLT + off] = make_short4(il[0], il[1], il[2], il[3]);
    }
}

// MFMA contract, phase B.
__global__ __launch_bounds__(256) void k_amfma(const unsigned short* __restrict__ AFa,
                                               const unsigned short* __restrict__ tA,
                                               float2* __restrict__ OF) {
    constexpr int SG = 8;
    __shared__ __align__(16) unsigned short bs[4 * SG * 16 * 8];
    int t = threadIdx.x;
    int wave = t >> 6, lane = t & 63;
    int rt0 = wave * 2;
    int colp = lane & 15, rowq = lane >> 4;
    int k = blockIdx.x >> 2, b = blockIdx.x & 3;
    int reg = (k >= 64) ? 1 : 0;
    const short8v* AFv = (const short8v*)(AFa + (size_t)reg * 6 * 2 * 8 * 512);
    const size_t PLA = 2 * 8 * 64;
    const short8v* bsv = (const short8v*)bs;
    size_t p0 = (size_t)blockIdx.x * 64;

    for (int pt = 0; pt < 4; ++pt) {
        __syncthreads();
        {
            const float4* src = (const float4*)tA;
            float4* dst = (float4*)bs;
            for (int e = t; e < 4 * SG * 16; e += 256) {
                int pl = e >> 7; int rem = e & 127;
                int g = rem >> 4, li = rem & 15;
                dst[e] = src[((size_t)pl * SG + g) * 32768 + p0 + pt * 16 + li];
            }
        }
        __syncthreads();
        float4v accR[2], accI[2];
#pragma unroll
        for (int rt = 0; rt < 2; ++rt) {
            accR[rt] = (float4v){0.f, 0.f, 0.f, 0.f};
            accI[rt] = (float4v){0.f, 0.f, 0.f, 0.f};
        }
#pragma unroll
        for (int kc = 0; kc < 2; ++kc) {
            int gi = kc * 4 + rowq;
            short8v Brh = bsv[((0 * SG + gi) << 4) + colp];
            short8v Brl = bsv[((1 * SG + gi) << 4) + colp];
            short8v Bih = bsv[((2 * SG + gi) << 4) + colp];
            short8v Bil = bsv[((3 * SG + gi) << 4) + colp];
#pragma unroll
            for (int rt = 0; rt < 2; ++rt) {
                size_t ab = ((size_t)kc * 8 + rt0 + rt) * 64 + lane;
                short8v A0 = AFv[0 * PLA + ab];
                short8v A1 = AFv[1 * PLA + ab];
                short8v A2 = AFv[2 * PLA + ab];
                short8v A3 = AFv[3 * PLA + ab];
                short8v A4 = AFv[4 * PLA + ab];
                short8v A5 = AFv[5 * PLA + ab];
                float4v r_ = accR[rt];
                r_ = __builtin_amdgcn_mfma_f32_16x16x32_bf16(A0, Brh, r_, 0, 0, 0);
                r_ = __builtin_amdgcn_mfma_f32_16x16x32_bf16(A0, Brl, r_, 0, 0, 0);
                r_ = __builtin_amdgcn_mfma_f32_16x16x32_bf16(A1, Brh, r_, 0, 0, 0);
                r_ = __builtin_amdgcn_mfma_f32_16x16x32_bf16(A4, Bih, r_, 0, 0, 0);
                r_ = __builtin_amdgcn_mfma_f32_16x16x32_bf16(A4, Bil, r_, 0, 0, 0);
                r_ = __builtin_amdgcn_mfma_f32_16x16x32_bf16(A5, Bih, r_, 0, 0, 0);
                accR[rt] = r_;
                float4v i_ = accI[rt];
                i_ = __builtin_amdgcn_mfma_f32_16x16x32_bf16(A2, Brh, i_, 0, 0, 0);
                i_ = __builtin_amdgcn_mfma_f32_16x16x32_bf16(A2, Brl, i_, 0, 0, 0);
                i_ = __builtin_amdgcn_mfma_f32_16x16x32_bf16(A3, Brh, i_, 0, 0, 0);
                i_ = __builtin_amdgcn_mfma_f32_16x16x32_bf16(A0, Bih, i_, 0, 0, 0);
                i_ = __builtin_amdgcn_mfma_f32_16x16x32_bf16(A0, Bil, i_, 0, 0, 0);
                i_ = __builtin_amdgcn_mfma_f32_16x16x32_bf16(A1, Bih, i_, 0, 0, 0);
                accI[rt] = i_;
            }
        }
        int m = pt * 16 + colp;
#pragma unroll
        for (int rt = 0; rt < 2; ++rt) {
            int o0 = (rt0 + rt) * 16 + rowq * 4;
#pragma unroll
            for (int q = 0; q < 4; ++q)
                OF[(size_t)k * 32768 + (size_t)b * 8192 + (size_t)(o0 + q) * 64 + m] =
                    make_float2(accR[rt][q], accI[rt][q]);
        }
    }
}

// OF fp32 [k][p] -> OFt 4 bf16 planes [k>>3][p][k&7]
__global__ __launch_bounds__(256) void k_repack(const float2* __restrict__ OF,
                                                unsigned short* __restrict__ OFt) {
    int t = threadIdx.x;
    size_t p = (size_t)blockIdx.x * 256 + t;
    int kg = blockIdx.y;
    short8v vrh, vrl, vih, vil;
#pragma unroll
    for (int j = 0; j < 8; ++j) {
        float2 v = OF[(size_t)(kg * 8 + j) * P_ + p];
        unsigned short h1 = f2bf(v.x);
        vrh[j] = (short)h1; vrl[j] = (short)f2bf(v.x - bf2f(h1));
        unsigned short h2 = f2bf(v.y);
        vih[j] = (short)h2; vil[j] = (short)f2bf(v.y - bf2f(h2));
    }
    short8v* dst = (short8v*)OFt;
    const size_t PL8 = (size_t)16 * 32768;
    size_t gi = (size_t)kg * 32768 + p;
    dst[0 * PL8 + gi] = vrh;
    dst[1 * PL8 + gi] = vrl;
    dst[2 * PL8 + gi] = vih;
    dst[3 * PL8 + gi] = vil;
}

// MFMA inverse W-DFT: out[(bo,h)][w] = Re(Z . E).
__global__ __launch_bounds__(256) void k_invWm(const float2* __restrict__ Z,
                                               const unsigned short* __restrict__ EF,
                                               float* __restrict__ out) {
    __shared__ __align__(16) unsigned short es[32768];   // 64 KB
    int t = threadIdx.x;
    {
        const float4* src = (const float4*)EF;
        float4* dst = (float4*)es;
#pragma unroll
        for (int i = 0; i < 16; ++i) dst[t + 256 * i] = src[t + 256 * i];   // 4096 f4 = 64 KB
    }
    __syncthreads();
    int wave = t >> 6, lane = t & 63;
    int colp = lane & 15, rowq = lane >> 4;
    int m = blockIdx.x * 4 + wave;           // mtile id (131072/16 = 8192)
    int h = m >> 5, bot = m & 31;

    short8v Zrh[2], Zrl[2], Zih[2], Zil[2];
    const float2* zp = Z + (size_t)h * 32768 + (size_t)(bot * 16 + colp) * 64;
#pragma unroll
    for (int kc = 0; kc < 2; ++kc) {
        const float4* zv = (const float4*)(zp + kc * 32 + 8 * rowq);
        float4 a = zv[0], b = zv[1], c = zv[2], d = zv[3];
        float re[8] = {a.x, a.z, b.x, b.z, c.x, c.z, d.x, d.z};
        float im[8] = {a.y, a.w, b.y, b.w, c.y, c.w, d.y, d.w};
#pragma unroll
        for (int j = 0; j < 8; ++j) {
            unsigned short h1 = f2bf(re[j]);
            Zrh[kc][j] = (short)h1; Zrl[kc][j] = (short)f2bf(re[j] - bf2f(h1));
            unsigned short h2 = f2bf(im[j]);
            Zih[kc][j] = (short)h2; Zil[kc][j] = (short)f2bf(im[j] - bf2f(h2));
        }
    }

    const short8v* esv = (const short8v*)es;
    size_t obase = ((size_t)(bot * 16 + rowq * 4) * 256 + h) * 256;
#pragma unroll
    for (int nt = 0; nt < 16; ++nt) {
        float4v acc = {0.f, 0.f, 0.f, 0.f};
#pragma unroll
        for (int kc = 0; kc < 2; ++kc) {
            short8v Er  = esv[((0 * 2 + kc) * 16 + nt) * 64 + lane];
            short8v nEi = esv[((1 * 2 + kc) * 16 + nt) * 64 + lane];
            acc = __builtin_amdgcn_mfma_f32_16x16x32_bf16(Zrh[kc], Er,  acc, 0, 0, 0);
            acc = __builtin_amdgcn_mfma_f32_16x16x32_bf16(Zrl[kc], Er,  acc, 0, 0, 0);
            acc = __builtin_amdgcn_mfma_f32_16x16x32_bf16(Zih[kc], nEi, acc, 0, 0, 0);
            acc = __builtin_amdgcn_mfma_f32_16x16x32_bf16(Zil[kc], nEi, acc, 0, 0, 0);
        }
        int w = nt * 16 + colp;
#pragma unroll
        for (int q = 0; q < 4; ++q)
            out[obase + (size_t)q * 65536 + w] = acc[q];
    }
}

extern "C" void kernel_launch(void* const* d_in, const int* in_sizes, int n_in,
                              void* d_out, int out_size, void* d_ws, size_t ws_size,
                              hipStream_t stream) {
    const float* x  = (const float*)d_in[0];
    const float* a1 = (const float*)d_in[1];
    const float* b1 = (const float*)d_in[2];
    const float* c1 = (const float*)d_in[3];
    const float* d1 = (const float*)d_in[4];
    const float* a2 = (const float*)d_in[5];
    const float* b2 = (const float*)d_in[6];
    const float* c2 = (const float*)d_in[7];
    const float* d2 = (const float*)d_in[8];
    float* out = (float*)d_out;
    float* wsf = (float*)d_ws;

    if (ws_size < WS_FLOATS * sizeof(float)) return;

    unsigned short* Yt  = (unsigned short*)(wsf + oYT);
    float2*         Zb  = (float2*)(wsf + oYT);          // Z aliases Yt region (after amfma)
    float2*         XF  = (float2*)(wsf + oXF);
    unsigned short* OFt = (unsigned short*)(wsf + oXF);  // OFt aliases XF (after contractA)
    float2*         OF  = (float2*)(wsf + oOF);
    unsigned short* EF  = (unsigned short*)(wsf + oOF);  // EF aliases OF (after repack)
    float2*         G   = (float2*)(wsf + oG);
    unsigned short* BF  = (unsigned short*)(wsf + oBF);
    unsigned short* AF1 = (unsigned short*)(wsf + oAF1);
    unsigned short* AF2 = (unsigned short*)(wsf + oAF2);
    unsigned short* bA  = (unsigned short*)(wsf + oYT);  // after cmfma1, Yt region is dead
    unsigned short* gB  = bA + 1048576;
    unsigned short* tA  = (unsigned short*)(wsf + oTA);
    unsigned short* AFa = (unsigned short*)(wsf + oG);   // overwrites G after prepBG

    k_prepT<<<1792, 256, 0, stream>>>(AF1, AF2, BF);
    k_g<<<1024, 256, 0, stream>>>(c1, d1, c2, d2, G);
    k_stage1m<<<2048, 256, 0, stream>>>(x, BF, Yt);
    k_cmfma<256, 2><<<512, 256, 0, stream>>>(AF1, Yt, XF);
    k_prepBG<<<7168, 256, 0, stream>>>(b1, b2, G, bA, gB);
    k_prepA<<<384, 256, 0, stream>>>(a1, a2, AFa);       // G dead after prepBG
    k_contractA<<<512, 256, 0, stream>>>(XF, bA, gB, tA);
    k_amfma<<<512, 256, 0, stream>>>(AFa, tA, OF);
    k_repack<<<dim3(128, 16), 256, 0, stream>>>(OF, OFt);
    k_prepE<<<128, 256, 0, stream>>>(EF);                // OF dead after repack
    k_cmfma<128, 4><<<512, 256, 0, stream>>>(AF2, OFt, Zb);
    k_invWm<<<2048, 256, 0, stream>>>(Zb, EF, out);

    (void)in_sizes; (void)n_in; (void)out_size;
}

// Round 11
// 301.932 us; speedup vs baseline: 1.0111x; 1.0111x over previous
//
#include <hip/hip_runtime.h>
#include <math.h>

// FactorizedSpectralConv2d: pruned-DFT + TT contraction, MFMA everywhere matmul-shaped.
//
//   k_prepT    : split-bf16 MFMA A-frag tables for FH / IH DFT matrices + B-frag table for FW
//   k_g        : g[r][j][x][y] = sum_k cc[j,x,k]*dc[k,y]
//   k_stage1m  : W-DFT of x via MFMA -> Yt 4 bf16 planes [h/8][p][8]
//                (v3: 32 rows/wave for BF-table amortization, transient B-frags,
//                 x bf16-hi only — rounding incoherent vs data)
//   k_cmfma    : XF[k][p] = sum_h FH[k][h] Yt[h][p]    (split-bf16 complex MFMA)
//   k_prepBG   : bf16 frag tables for b (A) and g (B) of the TT contraction
//   k_prepA    : split-bf16 A-frag table for the a (Cout x r1) epilogue GEMM (over dead G)
//   k_contractA: MFMA w-GEMM + fp32 t-update; t written as split-bf16 frag planes tA
//   k_amfma    : OF[o,(k,b,m)] = sum_i a[o,i] tA[i,(k,b,m)]   (split-bf16 MFMA)
//   k_repack   : OF fp32 -> OFt 4 bf16 planes [k/8][p][8]
//   k_prepE    : bf16 B-frag table for the inverse-W twiddle (into dead OF region)
//   k_cmfma    : Z[h][q] = sum_k IH[h][k] OFt[k][q]
//   k_invWm    : out[(b,o,h)][w] = Re(Z . E) via MFMA (Z split hi/lo on the fly)

#define TWO_PI 6.28318530717958647692f

typedef __attribute__((ext_vector_type(8))) short short8v;   // 8 bf16 (4 VGPRs)
typedef __attribute__((ext_vector_type(4))) float float4v;   // MFMA C/D

namespace {
constexpr size_t P_ = 32768;            // B*C*KW pixel batch width

// workspace float offsets
constexpr size_t oYT = 0;                     // Yt: 4 planes [32][32768][8] bf16 = 16.77M floats
                                              //   then bA/gB + tA (contract), then Z f2
constexpr size_t oTA = 1048576;               // tA: 4 planes [8][32768][8] bf16
constexpr size_t oXF = 16777216;              // XF f2 33.5MB; later OFt 4 planes [16][32768][8]
constexpr size_t oOF = 25165824;              // OF f2 33.5MB; later EF (invW twiddle frags)
constexpr size_t oBF = 33554432;              // FW B-frag table: 65536 shorts
constexpr size_t oAF1 = 33587200;             // FH frags: 196608 shorts
constexpr size_t oAF2 = 33685504;             // IH frags
constexpr size_t oG  = 33792000;              // [2][32][64][64] f2 ; AFa overwrites after prepBG
constexpr size_t WS_FLOATS = oG + 524288;     // ~137.3 MB
}

__device__ __forceinline__ unsigned short f2bf(float f) {   // RNE float->bf16 bits
    unsigned int u = __float_as_uint(f);
    unsigned int r = (u + 0x7FFFu + ((u >> 16) & 1u)) >> 16;
    return (unsigned short)r;
}
__device__ __forceinline__ float bf2f(unsigned short b) {
    return __uint_as_float(((unsigned int)b) << 16);
}

// Split-bf16 fragment tables for the DFT matrices (AF1 FH, AF2 IH, BF FW).
__global__ __launch_bounds__(256) void k_prepT(unsigned short* __restrict__ AF1,
                                               unsigned short* __restrict__ AF2,
                                               unsigned short* __restrict__ BF) {
    int idx = blockIdx.x * 256 + threadIdx.x;      // < 458752
    if (idx < 393216) {
        int tbl = (idx >= 196608);
        int id = tbl ? (idx - 196608) : idx;
        int e = id & 7, lane = (id >> 3) & 63;
        int pl = id >> 15;
        float ang;
        if (!tbl) {
            int rt = (id >> 9) & 7, kc = (id >> 12) & 7;
            int r = rt * 16 + (lane & 15);             // k-row (128)
            int s = kc * 32 + 8 * (lane >> 4) + e;     // h (256)
            int kh = r + ((r >= 64) ? 128 : 0);
            int ph = (kh * s) & 255;
            ang = -TWO_PI * (float)ph / 256.0f;
        } else {
            int rt = (id >> 9) & 15, kc = (id >> 13) & 3;
            int r = rt * 16 + (lane & 15);             // h (256)
            int s = kc * 32 + 8 * (lane >> 4) + e;     // k (128)
            int kh = s + ((s >= 64) ? 128 : 0);
            int ph = (kh * r) & 255;
            ang = TWO_PI * (float)ph / 256.0f;
        }
        float sn, cs; sincosf(ang, &sn, &cs);
        float base = (pl < 2) ? cs : ((pl < 4) ? sn : -sn);
        unsigned short hi = f2bf(base);
        unsigned short out = (pl & 1) ? f2bf(base - bf2f(hi)) : hi;
        (tbl ? AF2 : AF1)[id] = out;
    } else {
        int id = idx - 393216;                          // < 65536
        int e = id & 7, lane = (id >> 3) & 63;
        int nt = (id >> 9) & 3, kc = (id >> 11) & 7;
        int pl = id >> 14;                              // 0..3
        int kw = nt * 16 + (lane & 15);
        int w = kc * 32 + 8 * (lane >> 4) + e;
        int ph = (w * kw) & 255;
        float ang = -TWO_PI * (float)ph / 256.0f;
        float sn, cs; sincosf(ang, &sn, &cs);
        float base = (pl < 2) ? cs : sn;
        unsigned short hi = f2bf(base);
        unsigned short out = (pl & 1) ? f2bf(base - bf2f(hi)) : hi;
        BF[id] = out;
    }
}

// bf16-hi B-frag table for the inverse-W twiddle:
// EF[pl(2: Er, -Ei)][kc(2)][nt(16)][lane][e], E[kw][w] = s_kw/65536 * e^{+2pi i kw w/256}
__global__ __launch_bounds__(256) void k_prepE(unsigned short* __restrict__ EF) {
    int idx = blockIdx.x * 256 + threadIdx.x;      // < 32768
    int e = idx & 7, lane = (idx >> 3) & 63;
    int nt = (idx >> 9) & 15, kc = (idx >> 13) & 1, pl = idx >> 14;
    int w = nt * 16 + (lane & 15);
    int kw = kc * 32 + 8 * (lane >> 4) + e;
    int ph = (kw * w) & 255;
    float ang = TWO_PI * (float)ph / 256.0f;
    float sn, cs; sincosf(ang, &sn, &cs);
    float sc = ((kw == 0) ? 1.0f : 2.0f) / 65536.0f;
    float v = (pl == 0) ? (sc * cs) : (-sc * sn);
    EF[idx] = f2bf(v);
}

// g[r][j][x][y] = sum_k cc[j,x,k] * dc[k,y]
__global__ __launch_bounds__(256) void k_g(const float* __restrict__ c1, const float* __restrict__ d1,
                                           const float* __restrict__ c2, const float* __restrict__ d2,
                                           float2* __restrict__ G) {
    int idx = blockIdx.x * 256 + threadIdx.x;      // < 262144
    int r = idx >> 17;
    int rem = idx & 131071;
    int j = rem >> 12;
    int xy = rem & 4095;
    int xm = xy >> 6, ym = xy & 63;
    const float* cp = r ? c2 : c1;
    const float* dp = r ? d2 : d1;
    float sr = 0.f, si = 0.f;
    for (int kk = 0; kk < 32; ++kk) {
        float cr = cp[((j * 64 + xm) * 32 + kk) * 2 + 0];
        float ci = cp[((j * 64 + xm) * 32 + kk) * 2 + 1];
        float dr = dp[(kk * 64 + ym) * 2 + 0];
        float di = dp[(kk * 64 + ym) * 2 + 1];
        sr = fmaf(cr, dr, fmaf(-ci, di, sr));
        si = fmaf(cr, di, fmaf( ci, dr, si));
    }
    G[(size_t)(r * 32 + j) * 4096 + xy] = make_float2(sr, si);
}

// bf16 fragment tables for the contraction.
__global__ __launch_bounds__(256) void k_prepBG(const float* __restrict__ b1, const float* __restrict__ b2,
                                                const float2* __restrict__ G,
                                                unsigned short* __restrict__ bA,
                                                unsigned short* __restrict__ gB) {
    size_t idx = (size_t)blockIdx.x * 256 + threadIdx.x;
    if (idx < 1048576) {
        int e     = idx & 7;
        int lane  = (idx >> 3) & 63;
        int c     = (idx >> 9) & 127;
        int itile = (idx >> 16) & 3;
        int reg   = (idx >> 18) & 1;
        int plane = (idx >> 19) & 1;
        int i = itile * 16 + (lane & 15);
        int j = 8 * (lane >> 4) + e;
        const float* bp = reg ? b2 : b1;
        float v = bp[((size_t)(i * 128 + c) * 32 + j) * 2 + plane];
        bA[idx] = f2bf(v);
    } else if (idx < 1048576 + 786432) {
        size_t i2 = idx - 1048576;
        int e     = i2 & 7;
        int lane  = (i2 >> 3) & 63;
        int ytile = (i2 >> 9) & 3;
        int x     = (i2 >> 11) & 63;
        int reg   = (i2 >> 17) & 1;
        int plane = (int)(i2 >> 18);           // 0,1,2
        int y = ytile * 16 + (lane & 15);
        int j = 8 * (lane >> 4) + e;
        float2 gv = G[(size_t)(reg * 32 + j) * 4096 + x * 64 + y];
        float v = (plane == 0) ? gv.x : ((plane == 1) ? gv.y : -gv.y);
        gB[i2] = f2bf(v);
    }
}

// Split-bf16 A-frag table for the a-epilogue GEMM (M=o=128, K=i=64).
__global__ __launch_bounds__(256) void k_prepA(const float* __restrict__ a1, const float* __restrict__ a2,
                                               unsigned short* __restrict__ AFa) {
    int idx = blockIdx.x * 256 + threadIdx.x;      // < 98304
    int e = idx & 7, lane = (idx >> 3) & 63;
    int rt = (idx >> 9) & 7, kc = (idx >> 12) & 1;
    int plreg = idx >> 13;                          // 0..11
    int reg = plreg / 6, pl = plreg % 6;
    int o = rt * 16 + (lane & 15);
    int i = kc * 32 + 8 * (lane >> 4) + e;
    const float* ap = reg ? a2 : a1;
    float ar = ap[(o * 64 + i) * 2 + 0];
    float ai = ap[(o * 64 + i) * 2 + 1];
    float base = (pl < 2) ? ar : ((pl < 4) ? ai : -ai);
    unsigned short hi = f2bf(base);
    unsigned short out = (pl & 1) ? f2bf(base - bf2f(hi)) : hi;
    AFa[idx] = out;
}

// MFMA W-DFT v3: wave = 2 mtiles (32 rows, BF amortization), grid 1024;
// transient per-(kc,nt) B-frags shared by both mtiles; x bf16-hi only (4 MFMAs/nt/rt);
// x prefetched one kc ahead.
__global__ __launch_bounds__(256) void k_stage1m(const float* __restrict__ x,
                                                 const unsigned short* __restrict__ BF,
                                                 unsigned short* __restrict__ Yt) {
    int t = threadIdx.x;
    int wave = t >> 6, lane = t & 63;
    size_t row0 = (size_t)blockIdx.x * 128 + (size_t)wave * 32;
    int colp = lane & 15, rowq = lane >> 4;
    const short8v* BFv = (const short8v*)BF;
    const size_t PLB = 8 * 4 * 64;

    float4v accR[2][4], accI[2][4];
#pragma unroll
    for (int rt = 0; rt < 2; ++rt)
#pragma unroll
        for (int nt = 0; nt < 4; ++nt) {
            accR[rt][nt] = (float4v){0.f, 0.f, 0.f, 0.f};
            accI[rt][nt] = (float4v){0.f, 0.f, 0.f, 0.f};
        }

    const float* xb0 = x + (row0 + colp) * 256 + 8 * rowq;
    const float* xb1 = x + (row0 + 16 + colp) * 256 + 8 * rowq;
    float4 nv[2][2];
    nv[0][0] = *(const float4*)(xb0);  nv[0][1] = *(const float4*)(xb0 + 4);
    nv[1][0] = *(const float4*)(xb1);  nv[1][1] = *(const float4*)(xb1 + 4);

    for (int kc = 0; kc < 8; ++kc) {
        short8v xh[2];
#pragma unroll
        for (int rt = 0; rt < 2; ++rt) {
            float4 v0 = nv[rt][0], v1 = nv[rt][1];
            float vv[8] = {v0.x, v0.y, v0.z, v0.w, v1.x, v1.y, v1.z, v1.w};
#pragma unroll
            for (int j = 0; j < 8; ++j) xh[rt][j] = (short)f2bf(vv[j]);
        }
        if (kc < 7) {                     // prefetch next chunk under this chunk's MFMAs
            nv[0][0] = *(const float4*)(xb0 + (kc + 1) * 32);
            nv[0][1] = *(const float4*)(xb0 + (kc + 1) * 32 + 4);
            nv[1][0] = *(const float4*)(xb1 + (kc + 1) * 32);
            nv[1][1] = *(const float4*)(xb1 + (kc + 1) * 32 + 4);
        }
#pragma unroll
        for (int nt = 0; nt < 4; ++nt) {
            size_t bb = ((size_t)kc * 4 + nt) * 64 + lane;
            short8v Bch = BFv[0 * PLB + bb];
            short8v Bcl = BFv[1 * PLB + bb];
            short8v Bsh = BFv[2 * PLB + bb];
            short8v Bsl = BFv[3 * PLB + bb];
#pragma unroll
            for (int rt = 0; rt < 2; ++rt) {
                float4v r_ = accR[rt][nt];
                r_ = __builtin_amdgcn_mfma_f32_16x16x32_bf16(xh[rt], Bch, r_, 0, 0, 0);
                r_ = __builtin_amdgcn_mfma_f32_16x16x32_bf16(xh[rt], Bcl, r_, 0, 0, 0);
                accR[rt][nt] = r_;
                float4v i_ = accI[rt][nt];
                i_ = __builtin_amdgcn_mfma_f32_16x16x32_bf16(xh[rt], Bsh, i_, 0, 0, 0);
                i_ = __builtin_amdgcn_mfma_f32_16x16x32_bf16(xh[rt], Bsl, i_, 0, 0, 0);
                accI[rt][nt] = i_;
            }
        }
    }

    // write split-bf16 Yt: D row=(lane>>4)*4+q -> x-row, col=lane&15 -> kw
    short* Yts = (short*)Yt;
    const size_t PLY = (size_t)32 * 32768 * 8;
#pragma unroll
    for (int rt = 0; rt < 2; ++rt) {
        size_t xrow0 = row0 + rt * 16 + rowq * 4;
        int h = (int)(xrow0 & 255), bc = (int)(xrow0 >> 8);
        size_t gbase = (size_t)(h >> 3) * 32768;
        int e0 = h & 7;                               // 0 or 4
#pragma unroll
        for (int nt = 0; nt < 4; ++nt) {
            size_t p = (size_t)bc * 64 + nt * 16 + colp;
            size_t off = (gbase + p) * 8 + e0;
            float4v R = accR[rt][nt], I = accI[rt][nt];
            short rh[4], rl[4], ih[4], il[4];
#pragma unroll
            for (int q = 0; q < 4; ++q) {
                unsigned short h1 = f2bf(R[q]);
                rh[q] = (short)h1; rl[q] = (short)f2bf(R[q] - bf2f(h1));
                unsigned short h2 = f2bf(I[q]);
                ih[q] = (short)h2; il[q] = (short)f2bf(I[q] - bf2f(h2));
            }
            *(short4*)&Yts[0 * PLY + off] = make_short4(rh[0], rh[1], rh[2], rh[3]);
            *(short4*)&Yts[1 * PLY + off] = make_short4(rl[0], rl[1], rl[2], rl[3]);
            *(short4*)&Yts[2 * PLY + off] = make_short4(ih[0], ih[1], ih[2], ih[3]);
            *(short4*)&Yts[3 * PLY + off] = make_short4(il[0], il[1], il[2], il[3]);
        }
    }
}

// Split-bf16 complex MFMA GEMM: Out[r][p] = sum_s T[r][s] * D[s][p].
template<int S, int RT_W>
__global__ __launch_bounds__(256) void k_cmfma(const unsigned short* __restrict__ AF,
                                               const unsigned short* __restrict__ Bt,
                                               float2* __restrict__ Out) {
    constexpr int KC = S / 32;
    constexpr int SG = S / 8;
    constexpr int RTOT = RT_W * 4;
    __shared__ __align__(16) unsigned short bs[4 * SG * 16 * 8];
    int t = threadIdx.x;
    int wave = t >> 6, lane = t & 63;
    int rt0 = wave * RT_W;
    int colp = lane & 15, rowq = lane >> 4;
    const short8v* AFv = (const short8v*)AF;
    const short8v* bsv = (const short8v*)bs;
    const size_t PLA = (size_t)KC * RTOT * 64;

    for (int pt = 0; pt < 4; ++pt) {
        int p0 = blockIdx.x * 64 + pt * 16;
        __syncthreads();
        {
            const float4* src = (const float4*)Bt;
            float4* dst = (float4*)bs;
            for (int e = t; e < 4 * SG * 16; e += 256) {
                int pl = e / (SG * 16); int rem = e - pl * (SG * 16);
                int g = rem >> 4, li = rem & 15;
                dst[e] = src[((size_t)pl * SG + g) * 32768 + p0 + li];
            }
        }
        __syncthreads();
        float4v accR[RT_W], accI[RT_W];
#pragma unroll
        for (int rt = 0; rt < RT_W; ++rt) {
            accR[rt] = (float4v){0.f, 0.f, 0.f, 0.f};
            accI[rt] = (float4v){0.f, 0.f, 0.f, 0.f};
        }
#pragma unroll
        for (int kc = 0; kc < KC; ++kc) {
            int gi = kc * 4 + rowq;
            short8v Brh = bsv[((0 * SG + gi) << 4) + colp];
            short8v Brl = bsv[((1 * SG + gi) << 4) + colp];
            short8v Bih = bsv[((2 * SG + gi) << 4) + colp];
            short8v Bil = bsv[((3 * SG + gi) << 4) + colp];
#pragma unroll
            for (int rt = 0; rt < RT_W; ++rt) {
                size_t ab = ((size_t)kc * RTOT + rt0 + rt) * 64 + lane;
                short8v A0 = AFv[0 * PLA + ab];
                short8v A1 = AFv[1 * PLA + ab];
                short8v A2 = AFv[2 * PLA + ab];
                short8v A3 = AFv[3 * PLA + ab];
                short8v A4 = AFv[4 * PLA + ab];
                short8v A5 = AFv[5 * PLA + ab];
                float4v r_ = accR[rt];
                r_ = __builtin_amdgcn_mfma_f32_16x16x32_bf16(A0, Brh, r_, 0, 0, 0);
                r_ = __builtin_amdgcn_mfma_f32_16x16x32_bf16(A0, Brl, r_, 0, 0, 0);
                r_ = __builtin_amdgcn_mfma_f32_16x16x32_bf16(A1, Brh, r_, 0, 0, 0);
                r_ = __builtin_amdgcn_mfma_f32_16x16x32_bf16(A4, Bih, r_, 0, 0, 0);
                r_ = __builtin_amdgcn_mfma_f32_16x16x32_bf16(A4, Bil, r_, 0, 0, 0);
                r_ = __builtin_amdgcn_mfma_f32_16x16x32_bf16(A5, Bih, r_, 0, 0, 0);
                accR[rt] = r_;
                float4v i_ = accI[rt];
                i_ = __builtin_amdgcn_mfma_f32_16x16x32_bf16(A2, Brh, i_, 0, 0, 0);
                i_ = __builtin_amdgcn_mfma_f32_16x16x32_bf16(A2, Brl, i_, 0, 0, 0);
                i_ = __builtin_amdgcn_mfma_f32_16x16x32_bf16(A3, Brh, i_, 0, 0, 0);
                i_ = __builtin_amdgcn_mfma_f32_16x16x32_bf16(A0, Bih, i_, 0, 0, 0);
                i_ = __builtin_amdgcn_mfma_f32_16x16x32_bf16(A0, Bil, i_, 0, 0, 0);
                i_ = __builtin_amdgcn_mfma_f32_16x16x32_bf16(A1, Bih, i_, 0, 0, 0);
                accI[rt] = i_;
            }
        }
#pragma unroll
        for (int rt = 0; rt < RT_W; ++rt) {
            int rbase = (rt0 + rt) * 16 + rowq * 4;
#pragma unroll
            for (int q = 0; q < 4; ++q)
                Out[(size_t)(rbase + q) * P_ + p0 + colp] = make_float2(accR[rt][q], accI[rt][q]);
        }
    }
}

// MFMA contract, phase A.
__global__ __launch_bounds__(256) void k_contractA(const float2* __restrict__ XF,
                                                   const unsigned short* __restrict__ bA,
                                                   const unsigned short* __restrict__ gB,
                                                   unsigned short* __restrict__ tA) {
    int t = threadIdx.x;
    int k = blockIdx.x >> 2;
    int ytile = blockIdx.x & 3;
    int y0 = ytile << 4;
    int reg = (k >= 64) ? 1 : 0;
    int x = k & 63;
    int itile = t >> 6, lane = t & 63;
    int ylane = lane & 15, qg = lane >> 4;

    const short8v* gBv = (const short8v*)gB;
    short8v g_r  = gBv[(((size_t)(0 * 2 + reg) * 64 + x) * 4 + ytile) * 64 + lane];
    short8v g_i  = gBv[(((size_t)(1 * 2 + reg) * 64 + x) * 4 + ytile) * 64 + lane];
    short8v g_ni = gBv[(((size_t)(2 * 2 + reg) * 64 + x) * 4 + ytile) * 64 + lane];

    const short8v* bAv = (const short8v*)bA;
    size_t aR = (((size_t)(0 * 2 + reg) * 4 + itile) * 128) * 64 + lane;
    size_t aI = (((size_t)(1 * 2 + reg) * 4 + itile) * 128) * 64 + lane;

    const float2* xfp = XF + (size_t)k * 32768 + y0 + ylane;

    float tr[4][4], ti[4][4];
#pragma unroll
    for (int q = 0; q < 4; ++q)
#pragma unroll
        for (int b = 0; b < 4; ++b) { tr[q][b] = 0.f; ti[q][b] = 0.f; }

#pragma unroll 2
    for (int c = 0; c < 128; ++c) {
        short8v av = bAv[aR + (size_t)c * 64];
        short8v aw = bAv[aI + (size_t)c * 64];
        float4v z4 = {0.f, 0.f, 0.f, 0.f};
        float4v wr = __builtin_amdgcn_mfma_f32_16x16x32_bf16(av, g_r, z4, 0, 0, 0);
        wr = __builtin_amdgcn_mfma_f32_16x16x32_bf16(aw, g_ni, wr, 0, 0, 0);
        float4v wi = __builtin_amdgcn_mfma_f32_16x16x32_bf16(av, g_i, z4, 0, 0, 0);
        wi = __builtin_amdgcn_mfma_f32_16x16x32_bf16(aw, g_r, wi, 0, 0, 0);
#pragma unroll
        for (int b = 0; b < 4; ++b) {
            float2 xv = xfp[(size_t)b * 8192 + (size_t)c * 64];
#pragma unroll
            for (int q = 0; q < 4; ++q) {
                tr[q][b] = fmaf(wr[q], xv.x, fmaf(-wi[q], xv.y, tr[q][b]));
                ti[q][b] = fmaf(wr[q], xv.y, fmaf( wi[q], xv.x, ti[q][b]));
            }
        }
    }

    short* tAs = (short*)tA;
    const size_t PLT = (size_t)8 * 32768 * 8;
    int gidx = itile * 2 + (qg >> 1);
    int e0 = (qg & 1) * 4;
#pragma unroll
    for (int b = 0; b < 4; ++b) {
        size_t col = (size_t)k * 256 + (size_t)b * 64 + y0 + ylane;
        size_t off = ((size_t)gidx * 32768 + col) * 8 + e0;
        short rh[4], rl[4], ih[4], il[4];
#pragma unroll
        for (int q = 0; q < 4; ++q) {
            unsigned short h1 = f2bf(tr[q][b]);
            rh[q] = (short)h1; rl[q] = (short)f2bf(tr[q][b] - bf2f(h1));
            unsigned short h2 = f2bf(ti[q][b]);
            ih[q] = (short)h2; il[q] = (short)f2bf(ti[q][b] - bf2f(h2));
        }
        *(short4*)&tAs[0 * PLT + off] = make_short4(rh[0], rh[1], rh[2], rh[3]);
        *(short4*)&tAs[1 * PLT + off] = make_short4(rl[0], rl[1], rl[2], rl[3]);
        *(short4*)&tAs[2 * PLT + off] = make_short4(ih[0], ih[1], ih[2], ih[3]);
        *(short4*)&tAs[3 * PLT + off] = make_short4(il[0], il[1], il[2], il[3]);
    }
}

// MFMA contract, phase B.
__global__ __launch_bounds__(256) void k_amfma(const unsigned short* __restrict__ AFa,
                                               const unsigned short* __restrict__ tA,
                                               float2* __restrict__ OF) {
    constexpr int SG = 8;
    __shared__ __align__(16) unsigned short bs[4 * SG * 16 * 8];
    int t = threadIdx.x;
    int wave = t >> 6, lane = t & 63;
    int rt0 = wave * 2;
    int colp = lane & 15, rowq = lane >> 4;
    int k = blockIdx.x >> 2, b = blockIdx.x & 3;
    int reg = (k >= 64) ? 1 : 0;
    const short8v* AFv = (const short8v*)(AFa + (size_t)reg * 6 * 2 * 8 * 512);
    const size_t PLA = 2 * 8 * 64;
    const short8v* bsv = (const short8v*)bs;
    size_t p0 = (size_t)blockIdx.x * 64;

    for (int pt = 0; pt < 4; ++pt) {
        __syncthreads();
        {
            const float4* src = (const float4*)tA;
            float4* dst = (float4*)bs;
            for (int e = t; e < 4 * SG * 16; e += 256) {
                int pl = e >> 7; int rem = e & 127;
                int g = rem >> 4, li = rem & 15;
                dst[e] = src[((size_t)pl * SG + g) * 32768 + p0 + pt * 16 + li];
            }
        }
        __syncthreads();
        float4v accR[2], accI[2];
#pragma unroll
        for (int rt = 0; rt < 2; ++rt) {
            accR[rt] = (float4v){0.f, 0.f, 0.f, 0.f};
            accI[rt] = (float4v){0.f, 0.f, 0.f, 0.f};
        }
#pragma unroll
        for (int kc = 0; kc < 2; ++kc) {
            int gi = kc * 4 + rowq;
            short8v Brh = bsv[((0 * SG + gi) << 4) + colp];
            short8v Brl = bsv[((1 * SG + gi) << 4) + colp];
            short8v Bih = bsv[((2 * SG + gi) << 4) + colp];
            short8v Bil = bsv[((3 * SG + gi) << 4) + colp];
#pragma unroll
            for (int rt = 0; rt < 2; ++rt) {
                size_t ab = ((size_t)kc * 8 + rt0 + rt) * 64 + lane;
                short8v A0 = AFv[0 * PLA + ab];
                short8v A1 = AFv[1 * PLA + ab];
                short8v A2 = AFv[2 * PLA + ab];
                short8v A3 = AFv[3 * PLA + ab];
                short8v A4 = AFv[4 * PLA + ab];
                short8v A5 = AFv[5 * PLA + ab];
                float4v r_ = accR[rt];
                r_ = __builtin_amdgcn_mfma_f32_16x16x32_bf16(A0, Brh, r_, 0, 0, 0);
                r_ = __builtin_amdgcn_mfma_f32_16x16x32_bf16(A0, Brl, r_, 0, 0, 0);
                r_ = __builtin_amdgcn_mfma_f32_16x16x32_bf16(A1, Brh, r_, 0, 0, 0);
                r_ = __builtin_amdgcn_mfma_f32_16x16x32_bf16(A4, Bih, r_, 0, 0, 0);
                r_ = __builtin_amdgcn_mfma_f32_16x16x32_bf16(A4, Bil, r_, 0, 0, 0);
                r_ = __builtin_amdgcn_mfma_f32_16x16x32_bf16(A5, Bih, r_, 0, 0, 0);
                accR[rt] = r_;
                float4v i_ = accI[rt];
                i_ = __builtin_amdgcn_mfma_f32_16x16x32_bf16(A2, Brh, i_, 0, 0, 0);
                i_ = __builtin_amdgcn_mfma_f32_16x16x32_bf16(A2, Brl, i_, 0, 0, 0);
                i_ = __builtin_amdgcn_mfma_f32_16x16x32_bf16(A3, Brh, i_, 0, 0, 0);
                i_ = __builtin_amdgcn_mfma_f32_16x16x32_bf16(A0, Bih, i_, 0, 0, 0);
                i_ = __builtin_amdgcn_mfma_f32_16x16x32_bf16(A0, Bil, i_, 0, 0, 0);
                i_ = __builtin_amdgcn_mfma_f32_16x16x32_bf16(A1, Bih, i_, 0, 0, 0);
                accI[rt] = i_;
            }
        }
        int m = pt * 16 + colp;
#pragma unroll
        for (int rt = 0; rt < 2; ++rt) {
            int o0 = (rt0 + rt) * 16 + rowq * 4;
#pragma unroll
            for (int q = 0; q < 4; ++q)
                OF[(size_t)k * 32768 + (size_t)b * 8192 + (size_t)(o0 + q) * 64 + m] =
                    make_float2(accR[rt][q], accI[rt][q]);
        }
    }
}

// OF fp32 [k][p] -> OFt 4 bf16 planes [k>>3][p][k&7]
__global__ __launch_bounds__(256) void k_repack(const float2* __restrict__ OF,
                                                unsigned short* __restrict__ OFt) {
    int t = threadIdx.x;
    size_t p = (size_t)blockIdx.x * 256 + t;
    int kg = blockIdx.y;
    short8v vrh, vrl, vih, vil;
#pragma unroll
    for (int j = 0; j < 8; ++j) {
        float2 v = OF[(size_t)(kg * 8 + j) * P_ + p];
        unsigned short h1 = f2bf(v.x);
        vrh[j] = (short)h1; vrl[j] = (short)f2bf(v.x - bf2f(h1));
        unsigned short h2 = f2bf(v.y);
        vih[j] = (short)h2; vil[j] = (short)f2bf(v.y - bf2f(h2));
    }
    short8v* dst = (short8v*)OFt;
    const size_t PL8 = (size_t)16 * 32768;
    size_t gi = (size_t)kg * 32768 + p;
    dst[0 * PL8 + gi] = vrh;
    dst[1 * PL8 + gi] = vrl;
    dst[2 * PL8 + gi] = vih;
    dst[3 * PL8 + gi] = vil;
}

// MFMA inverse W-DFT: out[(bo,h)][w] = Re(Z . E).
__global__ __launch_bounds__(256) void k_invWm(const float2* __restrict__ Z,
                                               const unsigned short* __restrict__ EF,
                                               float* __restrict__ out) {
    __shared__ __align__(16) unsigned short es[32768];   // 64 KB
    int t = threadIdx.x;
    {
        const float4* src = (const float4*)EF;
        float4* dst = (float4*)es;
#pragma unroll
        for (int i = 0; i < 16; ++i) dst[t + 256 * i] = src[t + 256 * i];   // 4096 f4 = 64 KB
    }
    __syncthreads();
    int wave = t >> 6, lane = t & 63;
    int colp = lane & 15, rowq = lane >> 4;
    int m = blockIdx.x * 4 + wave;           // mtile id (131072/16 = 8192)
    int h = m >> 5, bot = m & 31;

    short8v Zrh[2], Zrl[2], Zih[2], Zil[2];
    const float2* zp = Z + (size_t)h * 32768 + (size_t)(bot * 16 + colp) * 64;
#pragma unroll
    for (int kc = 0; kc < 2; ++kc) {
        const float4* zv = (const float4*)(zp + kc * 32 + 8 * rowq);
        float4 a = zv[0], b = zv[1], c = zv[2], d = zv[3];
        float re[8] = {a.x, a.z, b.x, b.z, c.x, c.z, d.x, d.z};
        float im[8] = {a.y, a.w, b.y, b.w, c.y, c.w, d.y, d.w};
#pragma unroll
        for (int j = 0; j < 8; ++j) {
            unsigned short h1 = f2bf(re[j]);
            Zrh[kc][j] = (short)h1; Zrl[kc][j] = (short)f2bf(re[j] - bf2f(h1));
            unsigned short h2 = f2bf(im[j]);
            Zih[kc][j] = (short)h2; Zil[kc][j] = (short)f2bf(im[j] - bf2f(h2));
        }
    }

    const short8v* esv = (const short8v*)es;
    size_t obase = ((size_t)(bot * 16 + rowq * 4) * 256 + h) * 256;
#pragma unroll
    for (int nt = 0; nt < 16; ++nt) {
        float4v acc = {0.f, 0.f, 0.f, 0.f};
#pragma unroll
        for (int kc = 0; kc < 2; ++kc) {
            short8v Er  = esv[((0 * 2 + kc) * 16 + nt) * 64 + lane];
            short8v nEi = esv[((1 * 2 + kc) * 16 + nt) * 64 + lane];
            acc = __builtin_amdgcn_mfma_f32_16x16x32_bf16(Zrh[kc], Er,  acc, 0, 0, 0);
            acc = __builtin_amdgcn_mfma_f32_16x16x32_bf16(Zrl[kc], Er,  acc, 0, 0, 0);
            acc = __builtin_amdgcn_mfma_f32_16x16x32_bf16(Zih[kc], nEi, acc, 0, 0, 0);
            acc = __builtin_amdgcn_mfma_f32_16x16x32_bf16(Zil[kc], nEi, acc, 0, 0, 0);
        }
        int w = nt * 16 + colp;
#pragma unroll
        for (int q = 0; q < 4; ++q)
            out[obase + (size_t)q * 65536 + w] = acc[q];
    }
}

extern "C" void kernel_launch(void* const* d_in, const int* in_sizes, int n_in,
                              void* d_out, int out_size, void* d_ws, size_t ws_size,
                              hipStream_t stream) {
    const float* x  = (const float*)d_in[0];
    const float* a1 = (const float*)d_in[1];
    const float* b1 = (const float*)d_in[2];
    const float* c1 = (const float*)d_in[3];
    const float* d1 = (const float*)d_in[4];
    const float* a2 = (const float*)d_in[5];
    const float* b2 = (const float*)d_in[6];
    const float* c2 = (const float*)d_in[7];
    const float* d2 = (const float*)d_in[8];
    float* out = (float*)d_out;
    float* wsf = (float*)d_ws;

    if (ws_size < WS_FLOATS * sizeof(float)) return;

    unsigned short* Yt  = (unsigned short*)(wsf + oYT);
    float2*         Zb  = (float2*)(wsf + oYT);          // Z aliases Yt region (after amfma)
    float2*         XF  = (float2*)(wsf + oXF);
    unsigned short* OFt = (unsigned short*)(wsf + oXF);  // OFt aliases XF (after contractA)
    float2*         OF  = (float2*)(wsf + oOF);
    unsigned short* EF  = (unsigned short*)(wsf + oOF);  // EF aliases OF (after repack)
    float2*         G   = (float2*)(wsf + oG);
    unsigned short* BF  = (unsigned short*)(wsf + oBF);
    unsigned short* AF1 = (unsigned short*)(wsf + oAF1);
    unsigned short* AF2 = (unsigned short*)(wsf + oAF2);
    unsigned short* bA  = (unsigned short*)(wsf + oYT);  // after cmfma1, Yt region is dead
    unsigned short* gB  = bA + 1048576;
    unsigned short* tA  = (unsigned short*)(wsf + oTA);
    unsigned short* AFa = (unsigned short*)(wsf + oG);   // overwrites G after prepBG

    k_prepT<<<1792, 256, 0, stream>>>(AF1, AF2, BF);
    k_g<<<1024, 256, 0, stream>>>(c1, d1, c2, d2, G);
    k_stage1m<<<1024, 256, 0, stream>>>(x, BF, Yt);
    k_cmfma<256, 2><<<512, 256, 0, stream>>>(AF1, Yt, XF);
    k_prepBG<<<7168, 256, 0, stream>>>(b1, b2, G, bA, gB);
    k_prepA<<<384, 256, 0, stream>>>(a1, a2, AFa);       // G dead after prepBG
    k_contractA<<<512, 256, 0, stream>>>(XF, bA, gB, tA);
    k_amfma<<<512, 256, 0, stream>>>(AFa, tA, OF);
    k_repack<<<dim3(128, 16), 256, 0, stream>>>(OF, OFt);
    k_prepE<<<128, 256, 0, stream>>>(EF);                // OF dead after repack
    k_cmfma<128, 4><<<512, 256, 0, stream>>>(AF2, OFt, Zb);
    k_invWm<<<2048, 256, 0, stream>>>(Zb, EF, out);

    (void)in_sizes; (void)n_in; (void)out_size;
}

// Round 12
// 283.658 us; speedup vs baseline: 1.0762x; 1.0644x over previous
//
#include <hip/hip_runtime.h>
#include <math.h>

// FactorizedSpectralConv2d: pruned-DFT + TT contraction, MFMA everywhere matmul-shaped.
//
//   k_prepT    : split-bf16 MFMA A-frag tables for FH / IH DFT matrices + B-frag table for FW
//   k_g        : g[r][j][x][y] = sum_k cc[j,x,k]*dc[k,y]
//   k_stage1m  : W-DFT of x via MFMA -> Yt 4 bf16 planes [h/8][p][8]
//                (v4: BF staged via LDS in 32KB barrier-synced phases — kills the
//                 L2-latency wall of v1-v3; x bf16-hi, prefetch 1 kc ahead)
//   k_cmfma    : XF[k][p] = sum_h FH[k][h] Yt[h][p]    (split-bf16 complex MFMA)
//   k_prepBG   : bf16 frag tables for b (A) and g (B) of the TT contraction
//   k_prepA    : split-bf16 A-frag table for the a (Cout x r1) epilogue GEMM (over dead G)
//   k_contractA: MFMA w-GEMM + fp32 t-update; t written as split-bf16 frag planes tA
//   k_amfma    : OF[o,(k,b,m)] = sum_i a[o,i] tA[i,(k,b,m)]   (split-bf16 MFMA)
//   k_repack   : OF fp32 -> OFt 4 bf16 planes [k/8][p][8]
//   k_prepE    : bf16 B-frag table for the inverse-W twiddle (into dead OF region)
//   k_cmfma    : Z[h][q] = sum_k IH[h][k] OFt[k][q]
//   k_invWm    : out[(b,o,h)][w] = Re(Z . E) via MFMA (Z split hi/lo on the fly)

#define TWO_PI 6.28318530717958647692f

typedef __attribute__((ext_vector_type(8))) short short8v;   // 8 bf16 (4 VGPRs)
typedef __attribute__((ext_vector_type(4))) float float4v;   // MFMA C/D

namespace {
constexpr size_t P_ = 32768;            // B*C*KW pixel batch width

// workspace float offsets
constexpr size_t oYT = 0;                     // Yt: 4 planes [32][32768][8] bf16 = 16.77M floats
                                              //   then bA/gB + tA (contract), then Z f2
constexpr size_t oTA = 1048576;               // tA: 4 planes [8][32768][8] bf16
constexpr size_t oXF = 16777216;              // XF f2 33.5MB; later OFt 4 planes [16][32768][8]
constexpr size_t oOF = 25165824;              // OF f2 33.5MB; later EF (invW twiddle frags)
constexpr size_t oBF = 33554432;              // FW B-frag table: 65536 shorts
constexpr size_t oAF1 = 33587200;             // FH frags: 196608 shorts
constexpr size_t oAF2 = 33685504;             // IH frags
constexpr size_t oG  = 33792000;              // [2][32][64][64] f2 ; AFa overwrites after prepBG
constexpr size_t WS_FLOATS = oG + 524288;     // ~137.3 MB
}

__device__ __forceinline__ unsigned short f2bf(float f) {   // RNE float->bf16 bits
    unsigned int u = __float_as_uint(f);
    unsigned int r = (u + 0x7FFFu + ((u >> 16) & 1u)) >> 16;
    return (unsigned short)r;
}
__device__ __forceinline__ float bf2f(unsigned short b) {
    return __uint_as_float(((unsigned int)b) << 16);
}

// Split-bf16 fragment tables for the DFT matrices (AF1 FH, AF2 IH, BF FW).
__global__ __launch_bounds__(256) void k_prepT(unsigned short* __restrict__ AF1,
                                               unsigned short* __restrict__ AF2,
                                               unsigned short* __restrict__ BF) {
    int idx = blockIdx.x * 256 + threadIdx.x;      // < 458752
    if (idx < 393216) {
        int tbl = (idx >= 196608);
        int id = tbl ? (idx - 196608) : idx;
        int e = id & 7, lane = (id >> 3) & 63;
        int pl = id >> 15;
        float ang;
        if (!tbl) {
            int rt = (id >> 9) & 7, kc = (id >> 12) & 7;
            int r = rt * 16 + (lane & 15);             // k-row (128)
            int s = kc * 32 + 8 * (lane >> 4) + e;     // h (256)
            int kh = r + ((r >= 64) ? 128 : 0);
            int ph = (kh * s) & 255;
            ang = -TWO_PI * (float)ph / 256.0f;
        } else {
            int rt = (id >> 9) & 15, kc = (id >> 13) & 3;
            int r = rt * 16 + (lane & 15);             // h (256)
            int s = kc * 32 + 8 * (lane >> 4) + e;     // k (128)
            int kh = s + ((s >= 64) ? 128 : 0);
            int ph = (kh * r) & 255;
            ang = TWO_PI * (float)ph / 256.0f;
        }
        float sn, cs; sincosf(ang, &sn, &cs);
        float base = (pl < 2) ? cs : ((pl < 4) ? sn : -sn);
        unsigned short hi = f2bf(base);
        unsigned short out = (pl & 1) ? f2bf(base - bf2f(hi)) : hi;
        (tbl ? AF2 : AF1)[id] = out;
    } else {
        int id = idx - 393216;                          // < 65536
        int e = id & 7, lane = (id >> 3) & 63;
        int nt = (id >> 9) & 3, kc = (id >> 11) & 7;
        int pl = id >> 14;                              // 0..3
        int kw = nt * 16 + (lane & 15);
        int w = kc * 32 + 8 * (lane >> 4) + e;
        int ph = (w * kw) & 255;
        float ang = -TWO_PI * (float)ph / 256.0f;
        float sn, cs; sincosf(ang, &sn, &cs);
        float base = (pl < 2) ? cs : sn;
        unsigned short hi = f2bf(base);
        unsigned short out = (pl & 1) ? f2bf(base - bf2f(hi)) : hi;
        BF[id] = out;
    }
}

// bf16-hi B-frag table for the inverse-W twiddle:
// EF[pl(2: Er, -Ei)][kc(2)][nt(16)][lane][e], E[kw][w] = s_kw/65536 * e^{+2pi i kw w/256}
__global__ __launch_bounds__(256) void k_prepE(unsigned short* __restrict__ EF) {
    int idx = blockIdx.x * 256 + threadIdx.x;      // < 32768
    int e = idx & 7, lane = (idx >> 3) & 63;
    int nt = (idx >> 9) & 15, kc = (idx >> 13) & 1, pl = idx >> 14;
    int w = nt * 16 + (lane & 15);
    int kw = kc * 32 + 8 * (lane >> 4) + e;
    int ph = (kw * w) & 255;
    float ang = TWO_PI * (float)ph / 256.0f;
    float sn, cs; sincosf(ang, &sn, &cs);
    float sc = ((kw == 0) ? 1.0f : 2.0f) / 65536.0f;
    float v = (pl == 0) ? (sc * cs) : (-sc * sn);
    EF[idx] = f2bf(v);
}

// g[r][j][x][y] = sum_k cc[j,x,k] * dc[k,y]
__global__ __launch_bounds__(256) void k_g(const float* __restrict__ c1, const float* __restrict__ d1,
                                           const float* __restrict__ c2, const float* __restrict__ d2,
                                           float2* __restrict__ G) {
    int idx = blockIdx.x * 256 + threadIdx.x;      // < 262144
    int r = idx >> 17;
    int rem = idx & 131071;
    int j = rem >> 12;
    int xy = rem & 4095;
    int xm = xy >> 6, ym = xy & 63;
    const float* cp = r ? c2 : c1;
    const float* dp = r ? d2 : d1;
    float sr = 0.f, si = 0.f;
    for (int kk = 0; kk < 32; ++kk) {
        float cr = cp[((j * 64 + xm) * 32 + kk) * 2 + 0];
        float ci = cp[((j * 64 + xm) * 32 + kk) * 2 + 1];
        float dr = dp[(kk * 64 + ym) * 2 + 0];
        float di = dp[(kk * 64 + ym) * 2 + 1];
        sr = fmaf(cr, dr, fmaf(-ci, di, sr));
        si = fmaf(cr, di, fmaf( ci, dr, si));
    }
    G[(size_t)(r * 32 + j) * 4096 + xy] = make_float2(sr, si);
}

// bf16 fragment tables for the contraction.
__global__ __launch_bounds__(256) void k_prepBG(const float* __restrict__ b1, const float* __restrict__ b2,
                                                const float2* __restrict__ G,
                                                unsigned short* __restrict__ bA,
                                                unsigned short* __restrict__ gB) {
    size_t idx = (size_t)blockIdx.x * 256 + threadIdx.x;
    if (idx < 1048576) {
        int e     = idx & 7;
        int lane  = (idx >> 3) & 63;
        int c     = (idx >> 9) & 127;
        int itile = (idx >> 16) & 3;
        int reg   = (idx >> 18) & 1;
        int plane = (idx >> 19) & 1;
        int i = itile * 16 + (lane & 15);
        int j = 8 * (lane >> 4) + e;
        const float* bp = reg ? b2 : b1;
        float v = bp[((size_t)(i * 128 + c) * 32 + j) * 2 + plane];
        bA[idx] = f2bf(v);
    } else if (idx < 1048576 + 786432) {
        size_t i2 = idx - 1048576;
        int e     = i2 & 7;
        int lane  = (i2 >> 3) & 63;
        int ytile = (i2 >> 9) & 3;
        int x     = (i2 >> 11) & 63;
        int reg   = (i2 >> 17) & 1;
        int plane = (int)(i2 >> 18);           // 0,1,2
        int y = ytile * 16 + (lane & 15);
        int j = 8 * (lane >> 4) + e;
        float2 gv = G[(size_t)(reg * 32 + j) * 4096 + x * 64 + y];
        float v = (plane == 0) ? gv.x : ((plane == 1) ? gv.y : -gv.y);
        gB[i2] = f2bf(v);
    }
}

// Split-bf16 A-frag table for the a-epilogue GEMM (M=o=128, K=i=64).
__global__ __launch_bounds__(256) void k_prepA(const float* __restrict__ a1, const float* __restrict__ a2,
                                               unsigned short* __restrict__ AFa) {
    int idx = blockIdx.x * 256 + threadIdx.x;      // < 98304
    int e = idx & 7, lane = (idx >> 3) & 63;
    int rt = (idx >> 9) & 7, kc = (idx >> 12) & 1;
    int plreg = idx >> 13;                          // 0..11
    int reg = plreg / 6, pl = plreg % 6;
    int o = rt * 16 + (lane & 15);
    int i = kc * 32 + 8 * (lane >> 4) + e;
    const float* ap = reg ? a2 : a1;
    float ar = ap[(o * 64 + i) * 2 + 0];
    float ai = ap[(o * 64 + i) * 2 + 1];
    float base = (pl < 2) ? ar : ((pl < 4) ? ai : -ai);
    unsigned short hi = f2bf(base);
    unsigned short out = (pl & 1) ? f2bf(base - bf2f(hi)) : hi;
    AFa[idx] = out;
}

// MFMA W-DFT v4: BF staged via LDS in 32KB barrier-synced phases (2 kc each).
// Block = 4 waves x 2 mtiles = 128 rows; grid 1024. x bf16-hi, prefetch 1 kc ahead.
__global__ __launch_bounds__(256) void k_stage1m(const float* __restrict__ x,
                                                 const unsigned short* __restrict__ BF,
                                                 unsigned short* __restrict__ Yt) {
    __shared__ __align__(16) unsigned short es[16384];   // 32 KB: [pl(4)][kcl(2)][nt(4)][lane(64)][e(8)]
    int t = threadIdx.x;
    int wave = t >> 6, lane = t & 63;
    size_t row0 = (size_t)blockIdx.x * 128 + (size_t)wave * 32;
    int colp = lane & 15, rowq = lane >> 4;
    const short8v* esv = (const short8v*)es;

    float4v accR[2][4], accI[2][4];
#pragma unroll
    for (int rt = 0; rt < 2; ++rt)
#pragma unroll
        for (int nt = 0; nt < 4; ++nt) {
            accR[rt][nt] = (float4v){0.f, 0.f, 0.f, 0.f};
            accI[rt][nt] = (float4v){0.f, 0.f, 0.f, 0.f};
        }

    const float* xb0 = x + (row0 + colp) * 256 + 8 * rowq;
    const float* xb1 = xb0 + 16 * 256;
    float4 nv[2][2];
    nv[0][0] = *(const float4*)(xb0);  nv[0][1] = *(const float4*)(xb0 + 4);
    nv[1][0] = *(const float4*)(xb1);  nv[1][1] = *(const float4*)(xb1 + 4);

    const float4* bf4 = (const float4*)BF;
    for (int ph = 0; ph < 4; ++ph) {
        __syncthreads();                  // previous phase's readers done
        {   // stage 2 kc x 4 planes x 4 nt x 64 lanes = 2048 float4 = 32 KB
#pragma unroll
            for (int i = 0; i < 8; ++i) {
                int idx = t + 256 * i;
                int li  = idx & 63;
                int nt  = (idx >> 6) & 3;
                int kcl = (idx >> 8) & 1;
                int pl  = idx >> 9;
                ((float4*)es)[idx] = bf4[((size_t)(pl * 8 + ph * 2 + kcl) * 4 + nt) * 64 + li];
            }
        }
        __syncthreads();
        for (int kcl = 0; kcl < 2; ++kcl) {
            int kc = ph * 2 + kcl;
            short8v xh[2];
#pragma unroll
            for (int rt = 0; rt < 2; ++rt) {
                float4 v0 = nv[rt][0], v1 = nv[rt][1];
                float vv[8] = {v0.x, v0.y, v0.z, v0.w, v1.x, v1.y, v1.z, v1.w};
#pragma unroll
                for (int j = 0; j < 8; ++j) xh[rt][j] = (short)f2bf(vv[j]);
            }
            if (kc < 7) {                 // prefetch next kc under this kc's MFMAs
                nv[0][0] = *(const float4*)(xb0 + (kc + 1) * 32);
                nv[0][1] = *(const float4*)(xb0 + (kc + 1) * 32 + 4);
                nv[1][0] = *(const float4*)(xb1 + (kc + 1) * 32);
                nv[1][1] = *(const float4*)(xb1 + (kc + 1) * 32 + 4);
            }
#pragma unroll
            for (int nt = 0; nt < 4; ++nt) {
                short8v Bch = esv[((0 * 2 + kcl) * 4 + nt) * 64 + lane];
                short8v Bcl = esv[((1 * 2 + kcl) * 4 + nt) * 64 + lane];
                short8v Bsh = esv[((2 * 2 + kcl) * 4 + nt) * 64 + lane];
                short8v Bsl = esv[((3 * 2 + kcl) * 4 + nt) * 64 + lane];
#pragma unroll
                for (int rt = 0; rt < 2; ++rt) {
                    float4v r_ = accR[rt][nt];
                    r_ = __builtin_amdgcn_mfma_f32_16x16x32_bf16(xh[rt], Bch, r_, 0, 0, 0);
                    r_ = __builtin_amdgcn_mfma_f32_16x16x32_bf16(xh[rt], Bcl, r_, 0, 0, 0);
                    accR[rt][nt] = r_;
                    float4v i_ = accI[rt][nt];
                    i_ = __builtin_amdgcn_mfma_f32_16x16x32_bf16(xh[rt], Bsh, i_, 0, 0, 0);
                    i_ = __builtin_amdgcn_mfma_f32_16x16x32_bf16(xh[rt], Bsl, i_, 0, 0, 0);
                    accI[rt][nt] = i_;
                }
            }
        }
    }

    // write split-bf16 Yt: D row=(lane>>4)*4+q -> x-row, col=lane&15 -> kw
    short* Yts = (short*)Yt;
    const size_t PLY = (size_t)32 * 32768 * 8;
#pragma unroll
    for (int rt = 0; rt < 2; ++rt) {
        size_t xrow0 = row0 + rt * 16 + rowq * 4;
        int h = (int)(xrow0 & 255), bc = (int)(xrow0 >> 8);
        size_t gbase = (size_t)(h >> 3) * 32768;
        int e0 = h & 7;                               // 0 or 4
#pragma unroll
        for (int nt = 0; nt < 4; ++nt) {
            size_t p = (size_t)bc * 64 + nt * 16 + colp;
            size_t off = (gbase + p) * 8 + e0;
            float4v R = accR[rt][nt], I = accI[rt][nt];
            short rh[4], rl[4], ih[4], il[4];
#pragma unroll
            for (int q = 0; q < 4; ++q) {
                unsigned short h1 = f2bf(R[q]);
                rh[q] = (short)h1; rl[q] = (short)f2bf(R[q] - bf2f(h1));
                unsigned short h2 = f2bf(I[q]);
                ih[q] = (short)h2; il[q] = (short)f2bf(I[q] - bf2f(h2));
            }
            *(short4*)&Yts[0 * PLY + off] = make_short4(rh[0], rh[1], rh[2], rh[3]);
            *(short4*)&Yts[1 * PLY + off] = make_short4(rl[0], rl[1], rl[2], rl[3]);
            *(short4*)&Yts[2 * PLY + off] = make_short4(ih[0], ih[1], ih[2], ih[3]);
            *(short4*)&Yts[3 * PLY + off] = make_short4(il[0], il[1], il[2], il[3]);
        }
    }
}

// Split-bf16 complex MFMA GEMM: Out[r][p] = sum_s T[r][s] * D[s][p].
template<int S, int RT_W>
__global__ __launch_bounds__(256) void k_cmfma(const unsigned short* __restrict__ AF,
                                               const unsigned short* __restrict__ Bt,
                                               float2* __restrict__ Out) {
    constexpr int KC = S / 32;
    constexpr int SG = S / 8;
    constexpr int RTOT = RT_W * 4;
    __shared__ __align__(16) unsigned short bs[4 * SG * 16 * 8];
    int t = threadIdx.x;
    int wave = t >> 6, lane = t & 63;
    int rt0 = wave * RT_W;
    int colp = lane & 15, rowq = lane >> 4;
    const short8v* AFv = (const short8v*)AF;
    const short8v* bsv = (const short8v*)bs;
    const size_t PLA = (size_t)KC * RTOT * 64;

    for (int pt = 0; pt < 4; ++pt) {
        int p0 = blockIdx.x * 64 + pt * 16;
        __syncthreads();
        {
            const float4* src = (const float4*)Bt;
            float4* dst = (float4*)bs;
            for (int e = t; e < 4 * SG * 16; e += 256) {
                int pl = e / (SG * 16); int rem = e - pl * (SG * 16);
                int g = rem >> 4, li = rem & 15;
                dst[e] = src[((size_t)pl * SG + g) * 32768 + p0 + li];
            }
        }
        __syncthreads();
        float4v accR[RT_W], accI[RT_W];
#pragma unroll
        for (int rt = 0; rt < RT_W; ++rt) {
            accR[rt] = (float4v){0.f, 0.f, 0.f, 0.f};
            accI[rt] = (float4v){0.f, 0.f, 0.f, 0.f};
        }
#pragma unroll
        for (int kc = 0; kc < KC; ++kc) {
            int gi = kc * 4 + rowq;
            short8v Brh = bsv[((0 * SG + gi) << 4) + colp];
            short8v Brl = bsv[((1 * SG + gi) << 4) + colp];
            short8v Bih = bsv[((2 * SG + gi) << 4) + colp];
            short8v Bil = bsv[((3 * SG + gi) << 4) + colp];
#pragma unroll
            for (int rt = 0; rt < RT_W; ++rt) {
                size_t ab = ((size_t)kc * RTOT + rt0 + rt) * 64 + lane;
                short8v A0 = AFv[0 * PLA + ab];
                short8v A1 = AFv[1 * PLA + ab];
                short8v A2 = AFv[2 * PLA + ab];
                short8v A3 = AFv[3 * PLA + ab];
                short8v A4 = AFv[4 * PLA + ab];
                short8v A5 = AFv[5 * PLA + ab];
                float4v r_ = accR[rt];
                r_ = __builtin_amdgcn_mfma_f32_16x16x32_bf16(A0, Brh, r_, 0, 0, 0);
                r_ = __builtin_amdgcn_mfma_f32_16x16x32_bf16(A0, Brl, r_, 0, 0, 0);
                r_ = __builtin_amdgcn_mfma_f32_16x16x32_bf16(A1, Brh, r_, 0, 0, 0);
                r_ = __builtin_amdgcn_mfma_f32_16x16x32_bf16(A4, Bih, r_, 0, 0, 0);
                r_ = __builtin_amdgcn_mfma_f32_16x16x32_bf16(A4, Bil, r_, 0, 0, 0);
                r_ = __builtin_amdgcn_mfma_f32_16x16x32_bf16(A5, Bih, r_, 0, 0, 0);
                accR[rt] = r_;
                float4v i_ = accI[rt];
                i_ = __builtin_amdgcn_mfma_f32_16x16x32_bf16(A2, Brh, i_, 0, 0, 0);
                i_ = __builtin_amdgcn_mfma_f32_16x16x32_bf16(A2, Brl, i_, 0, 0, 0);
                i_ = __builtin_amdgcn_mfma_f32_16x16x32_bf16(A3, Brh, i_, 0, 0, 0);
                i_ = __builtin_amdgcn_mfma_f32_16x16x32_bf16(A0, Bih, i_, 0, 0, 0);
                i_ = __builtin_amdgcn_mfma_f32_16x16x32_bf16(A0, Bil, i_, 0, 0, 0);
                i_ = __builtin_amdgcn_mfma_f32_16x16x32_bf16(A1, Bih, i_, 0, 0, 0);
                accI[rt] = i_;
            }
        }
#pragma unroll
        for (int rt = 0; rt < RT_W; ++rt) {
            int rbase = (rt0 + rt) * 16 + rowq * 4;
#pragma unroll
            for (int q = 0; q < 4; ++q)
                Out[(size_t)(rbase + q) * P_ + p0 + colp] = make_float2(accR[rt][q], accI[rt][q]);
        }
    }
}

// MFMA contract, phase A.
__global__ __launch_bounds__(256) void k_contractA(const float2* __restrict__ XF,
                                                   const unsigned short* __restrict__ bA,
                                                   const unsigned short* __restrict__ gB,
                                                   unsigned short* __restrict__ tA) {
    int t = threadIdx.x;
    int k = blockIdx.x >> 2;
    int ytile = blockIdx.x & 3;
    int y0 = ytile << 4;
    int reg = (k >= 64) ? 1 : 0;
    int x = k & 63;
    int itile = t >> 6, lane = t & 63;
    int ylane = lane & 15, qg = lane >> 4;

    const short8v* gBv = (const short8v*)gB;
    short8v g_r  = gBv[(((size_t)(0 * 2 + reg) * 64 + x) * 4 + ytile) * 64 + lane];
    short8v g_i  = gBv[(((size_t)(1 * 2 + reg) * 64 + x) * 4 + ytile) * 64 + lane];
    short8v g_ni = gBv[(((size_t)(2 * 2 + reg) * 64 + x) * 4 + ytile) * 64 + lane];

    const short8v* bAv = (const short8v*)bA;
    size_t aR = (((size_t)(0 * 2 + reg) * 4 + itile) * 128) * 64 + lane;
    size_t aI = (((size_t)(1 * 2 + reg) * 4 + itile) * 128) * 64 + lane;

    const float2* xfp = XF + (size_t)k * 32768 + y0 + ylane;

    float tr[4][4], ti[4][4];
#pragma unroll
    for (int q = 0; q < 4; ++q)
#pragma unroll
        for (int b = 0; b < 4; ++b) { tr[q][b] = 0.f; ti[q][b] = 0.f; }

#pragma unroll 2
    for (int c = 0; c < 128; ++c) {
        short8v av = bAv[aR + (size_t)c * 64];
        short8v aw = bAv[aI + (size_t)c * 64];
        float4v z4 = {0.f, 0.f, 0.f, 0.f};
        float4v wr = __builtin_amdgcn_mfma_f32_16x16x32_bf16(av, g_r, z4, 0, 0, 0);
        wr = __builtin_amdgcn_mfma_f32_16x16x32_bf16(aw, g_ni, wr, 0, 0, 0);
        float4v wi = __builtin_amdgcn_mfma_f32_16x16x32_bf16(av, g_i, z4, 0, 0, 0);
        wi = __builtin_amdgcn_mfma_f32_16x16x32_bf16(aw, g_r, wi, 0, 0, 0);
#pragma unroll
        for (int b = 0; b < 4; ++b) {
            float2 xv = xfp[(size_t)b * 8192 + (size_t)c * 64];
#pragma unroll
            for (int q = 0; q < 4; ++q) {
                tr[q][b] = fmaf(wr[q], xv.x, fmaf(-wi[q], xv.y, tr[q][b]));
                ti[q][b] = fmaf(wr[q], xv.y, fmaf( wi[q], xv.x, ti[q][b]));
            }
        }
    }

    short* tAs = (short*)tA;
    const size_t PLT = (size_t)8 * 32768 * 8;
    int gidx = itile * 2 + (qg >> 1);
    int e0 = (qg & 1) * 4;
#pragma unroll
    for (int b = 0; b < 4; ++b) {
        size_t col = (size_t)k * 256 + (size_t)b * 64 + y0 + ylane;
        size_t off = ((size_t)gidx * 32768 + col) * 8 + e0;
        short rh[4], rl[4], ih[4], il[4];
#pragma unroll
        for (int q = 0; q < 4; ++q) {
            unsigned short h1 = f2bf(tr[q][b]);
            rh[q] = (short)h1; rl[q] = (short)f2bf(tr[q][b] - bf2f(h1));
            unsigned short h2 = f2bf(ti[q][b]);
            ih[q] = (short)h2; il[q] = (short)f2bf(ti[q][b] - bf2f(h2));
        }
        *(short4*)&tAs[0 * PLT + off] = make_short4(rh[0], rh[1], rh[2], rh[3]);
        *(short4*)&tAs[1 * PLT + off] = make_short4(rl[0], rl[1], rl[2], rl[3]);
        *(short4*)&tAs[2 * PLT + off] = make_short4(ih[0], ih[1], ih[2], ih[3]);
        *(short4*)&tAs[3 * PLT + off] = make_short4(il[0], il[1], il[2], il[3]);
    }
}

// MFMA contract, phase B.
__global__ __launch_bounds__(256) void k_amfma(const unsigned short* __restrict__ AFa,
                                               const unsigned short* __restrict__ tA,
                                               float2* __restrict__ OF) {
    constexpr int SG = 8;
    __shared__ __align__(16) unsigned short bs[4 * SG * 16 * 8];
    int t = threadIdx.x;
    int wave = t >> 6, lane = t & 63;
    int rt0 = wave * 2;
    int colp = lane & 15, rowq = lane >> 4;
    int k = blockIdx.x >> 2, b = blockIdx.x & 3;
    int reg = (k >= 64) ? 1 : 0;
    const short8v* AFv = (const short8v*)(AFa + (size_t)reg * 6 * 2 * 8 * 512);
    const size_t PLA = 2 * 8 * 64;
    const short8v* bsv = (const short8v*)bs;
    size_t p0 = (size_t)blockIdx.x * 64;

    for (int pt = 0; pt < 4; ++pt) {
        __syncthreads();
        {
            const float4* src = (const float4*)tA;
            float4* dst = (float4*)bs;
            for (int e = t; e < 4 * SG * 16; e += 256) {
                int pl = e >> 7; int rem = e & 127;
                int g = rem >> 4, li = rem & 15;
                dst[e] = src[((size_t)pl * SG + g) * 32768 + p0 + pt * 16 + li];
            }
        }
        __syncthreads();
        float4v accR[2], accI[2];
#pragma unroll
        for (int rt = 0; rt < 2; ++rt) {
            accR[rt] = (float4v){0.f, 0.f, 0.f, 0.f};
            accI[rt] = (float4v){0.f, 0.f, 0.f, 0.f};
        }
#pragma unroll
        for (int kc = 0; kc < 2; ++kc) {
            int gi = kc * 4 + rowq;
            short8v Brh = bsv[((0 * SG + gi) << 4) + colp];
            short8v Brl = bsv[((1 * SG + gi) << 4) + colp];
            short8v Bih = bsv[((2 * SG + gi) << 4) + colp];
            short8v Bil = bsv[((3 * SG + gi) << 4) + colp];
#pragma unroll
            for (int rt = 0; rt < 2; ++rt) {
                size_t ab = ((size_t)kc * 8 + rt0 + rt) * 64 + lane;
                short8v A0 = AFv[0 * PLA + ab];
                short8v A1 = AFv[1 * PLA + ab];
                short8v A2 = AFv[2 * PLA + ab];
                short8v A3 = AFv[3 * PLA + ab];
                short8v A4 = AFv[4 * PLA + ab];
                short8v A5 = AFv[5 * PLA + ab];
                float4v r_ = accR[rt];
                r_ = __builtin_amdgcn_mfma_f32_16x16x32_bf16(A0, Brh, r_, 0, 0, 0);
                r_ = __builtin_amdgcn_mfma_f32_16x16x32_bf16(A0, Brl, r_, 0, 0, 0);
                r_ = __builtin_amdgcn_mfma_f32_16x16x32_bf16(A1, Brh, r_, 0, 0, 0);
                r_ = __builtin_amdgcn_mfma_f32_16x16x32_bf16(A4, Bih, r_, 0, 0, 0);
                r_ = __builtin_amdgcn_mfma_f32_16x16x32_bf16(A4, Bil, r_, 0, 0, 0);
                r_ = __builtin_amdgcn_mfma_f32_16x16x32_bf16(A5, Bih, r_, 0, 0, 0);
                accR[rt] = r_;
                float4v i_ = accI[rt];
                i_ = __builtin_amdgcn_mfma_f32_16x16x32_bf16(A2, Brh, i_, 0, 0, 0);
                i_ = __builtin_amdgcn_mfma_f32_16x16x32_bf16(A2, Brl, i_, 0, 0, 0);
                i_ = __builtin_amdgcn_mfma_f32_16x16x32_bf16(A3, Brh, i_, 0, 0, 0);
                i_ = __builtin_amdgcn_mfma_f32_16x16x32_bf16(A0, Bih, i_, 0, 0, 0);
                i_ = __builtin_amdgcn_mfma_f32_16x16x32_bf16(A0, Bil, i_, 0, 0, 0);
                i_ = __builtin_amdgcn_mfma_f32_16x16x32_bf16(A1, Bih, i_, 0, 0, 0);
                accI[rt] = i_;
            }
        }
        int m = pt * 16 + colp;
#pragma unroll
        for (int rt = 0; rt < 2; ++rt) {
            int o0 = (rt0 + rt) * 16 + rowq * 4;
#pragma unroll
            for (int q = 0; q < 4; ++q)
                OF[(size_t)k * 32768 + (size_t)b * 8192 + (size_t)(o0 + q) * 64 + m] =
                    make_float2(accR[rt][q], accI[rt][q]);
        }
    }
}

// OF fp32 [k][p] -> OFt 4 bf16 planes [k>>3][p][k&7]
__global__ __launch_bounds__(256) void k_repack(const float2* __restrict__ OF,
                                                unsigned short* __restrict__ OFt) {
    int t = threadIdx.x;
    size_t p = (size_t)blockIdx.x * 256 + t;
    int kg = blockIdx.y;
    short8v vrh, vrl, vih, vil;
#pragma unroll
    for (int j = 0; j < 8; ++j) {
        float2 v = OF[(size_t)(kg * 8 + j) * P_ + p];
        unsigned short h1 = f2bf(v.x);
        vrh[j] = (short)h1; vrl[j] = (short)f2bf(v.x - bf2f(h1));
        unsigned short h2 = f2bf(v.y);
        vih[j] = (short)h2; vil[j] = (short)f2bf(v.y - bf2f(h2));
    }
    short8v* dst = (short8v*)OFt;
    const size_t PL8 = (size_t)16 * 32768;
    size_t gi = (size_t)kg * 32768 + p;
    dst[0 * PL8 + gi] = vrh;
    dst[1 * PL8 + gi] = vrl;
    dst[2 * PL8 + gi] = vih;
    dst[3 * PL8 + gi] = vil;
}

// MFMA inverse W-DFT: out[(bo,h)][w] = Re(Z . E).
__global__ __launch_bounds__(256) void k_invWm(const float2* __restrict__ Z,
                                               const unsigned short* __restrict__ EF,
                                               float* __restrict__ out) {
    __shared__ __align__(16) unsigned short es[32768];   // 64 KB
    int t = threadIdx.x;
    {
        const float4* src = (const float4*)EF;
        float4* dst = (float4*)es;
#pragma unroll
        for (int i = 0; i < 16; ++i) dst[t + 256 * i] = src[t + 256 * i];   // 4096 f4 = 64 KB
    }
    __syncthreads();
    int wave = t >> 6, lane = t & 63;
    int colp = lane & 15, rowq = lane >> 4;
    int m = blockIdx.x * 4 + wave;           // mtile id (131072/16 = 8192)
    int h = m >> 5, bot = m & 31;

    short8v Zrh[2], Zrl[2], Zih[2], Zil[2];
    const float2* zp = Z + (size_t)h * 32768 + (size_t)(bot * 16 + colp) * 64;
#pragma unroll
    for (int kc = 0; kc < 2; ++kc) {
        const float4* zv = (const float4*)(zp + kc * 32 + 8 * rowq);
        float4 a = zv[0], b = zv[1], c = zv[2], d = zv[3];
        float re[8] = {a.x, a.z, b.x, b.z, c.x, c.z, d.x, d.z};
        float im[8] = {a.y, a.w, b.y, b.w, c.y, c.w, d.y, d.w};
#pragma unroll
        for (int j = 0; j < 8; ++j) {
            unsigned short h1 = f2bf(re[j]);
            Zrh[kc][j] = (short)h1; Zrl[kc][j] = (short)f2bf(re[j] - bf2f(h1));
            unsigned short h2 = f2bf(im[j]);
            Zih[kc][j] = (short)h2; Zil[kc][j] = (short)f2bf(im[j] - bf2f(h2));
        }
    }

    const short8v* esv = (const short8v*)es;
    size_t obase = ((size_t)(bot * 16 + rowq * 4) * 256 + h) * 256;
#pragma unroll
    for (int nt = 0; nt < 16; ++nt) {
        float4v acc = {0.f, 0.f, 0.f, 0.f};
#pragma unroll
        for (int kc = 0; kc < 2; ++kc) {
            short8v Er  = esv[((0 * 2 + kc) * 16 + nt) * 64 + lane];
            short8v nEi = esv[((1 * 2 + kc) * 16 + nt) * 64 + lane];
            acc = __builtin_amdgcn_mfma_f32_16x16x32_bf16(Zrh[kc], Er,  acc, 0, 0, 0);
            acc = __builtin_amdgcn_mfma_f32_16x16x32_bf16(Zrl[kc], Er,  acc, 0, 0, 0);
            acc = __builtin_amdgcn_mfma_f32_16x16x32_bf16(Zih[kc], nEi, acc, 0, 0, 0);
            acc = __builtin_amdgcn_mfma_f32_16x16x32_bf16(Zil[kc], nEi, acc, 0, 0, 0);
        }
        int w = nt * 16 + colp;
#pragma unroll
        for (int q = 0; q < 4; ++q)
            out[obase + (size_t)q * 65536 + w] = acc[q];
    }
}

extern "C" void kernel_launch(void* const* d_in, const int* in_sizes, int n_in,
                              void* d_out, int out_size, void* d_ws, size_t ws_size,
                              hipStream_t stream) {
    const float* x  = (const float*)d_in[0];
    const float* a1 = (const float*)d_in[1];
    const float* b1 = (const float*)d_in[2];
    const float* c1 = (const float*)d_in[3];
    const float* d1 = (const float*)d_in[4];
    const float* a2 = (const float*)d_in[5];
    const float* b2 = (const float*)d_in[6];
    const float* c2 = (const float*)d_in[7];
    const float* d2 = (const float*)d_in[8];
    float* out = (float*)d_out;
    float* wsf = (float*)d_ws;

    if (ws_size < WS_FLOATS * sizeof(float)) return;

    unsigned short* Yt  = (unsigned short*)(wsf + oYT);
    float2*         Zb  = (float2*)(wsf + oYT);          // Z aliases Yt region (after amfma)
    float2*         XF  = (float2*)(wsf + oXF);
    unsigned short* OFt = (unsigned short*)(wsf + oXF);  // OFt aliases XF (after contractA)
    float2*         OF  = (float2*)(wsf + oOF);
    unsigned short* EF  = (unsigned short*)(wsf + oOF);  // EF aliases OF (after repack)
    float2*         G   = (float2*)(wsf + oG);
    unsigned short* BF  = (unsigned short*)(wsf + oBF);
    unsigned short* AF1 = (unsigned short*)(wsf + oAF1);
    unsigned short* AF2 = (unsigned short*)(wsf + oAF2);
    unsigned short* bA  = (unsigned short*)(wsf + oYT);  // after cmfma1, Yt region is dead
    unsigned short* gB  = bA + 1048576;
    unsigned short* tA  = (unsigned short*)(wsf + oTA);
    unsigned short* AFa = (unsigned short*)(wsf + oG);   // overwrites G after prepBG

    k_prepT<<<1792, 256, 0, stream>>>(AF1, AF2, BF);
    k_g<<<1024, 256, 0, stream>>>(c1, d1, c2, d2, G);
    k_stage1m<<<1024, 256, 0, stream>>>(x, BF, Yt);
    k_cmfma<256, 2><<<512, 256, 0, stream>>>(AF1, Yt, XF);
    k_prepBG<<<7168, 256, 0, stream>>>(b1, b2, G, bA, gB);
    k_prepA<<<384, 256, 0, stream>>>(a1, a2, AFa);       // G dead after prepBG
    k_contractA<<<512, 256, 0, stream>>>(XF, bA, gB, tA);
    k_amfma<<<512, 256, 0, stream>>>(AFa, tA, OF);
    k_repack<<<dim3(128, 16), 256, 0, stream>>>(OF, OFt);
    k_prepE<<<128, 256, 0, stream>>>(EF);                // OF dead after repack
    k_cmfma<128, 4><<<512, 256, 0, stream>>>(AF2, OFt, Zb);
    k_invWm<<<2048, 256, 0, stream>>>(Zb, EF, out);

    (void)in_sizes; (void)n_in; (void)out_size;
}

// Round 13
// 245.761 us; speedup vs baseline: 1.2422x; 1.1542x over previous
//
#include <hip/hip_runtime.h>
#include <math.h>

// FactorizedSpectralConv2d: pruned-DFT + TT contraction, MFMA everywhere matmul-shaped.
//
//   k_prepT    : split-bf16 MFMA A-frag tables for FH / IH DFT matrices + B-frag table for FW
//   k_g        : g[r][j][x][y] = sum_k cc[j,x,k]*dc[k,y]
//   k_stage1m  : W-DFT of x via MFMA -> Yt 4 bf16 planes [h/8][p][8] (LDS-staged twiddles)
//   k_cmfma    : XF[k][p] = sum_h FH[k][h] Yt[h][p]    (split-bf16 complex MFMA)
//   k_prepBG   : bf16 frag tables for b (A) and g (B) of the TT contraction
//   k_prepA    : split-bf16 A-frag table for the a epilogue GEMM (over dead G, 1st half)
//   k_prepE    : bf16 B-frag table for the inverse-W twiddle (over dead G, 2nd half)
//   k_contractA: MFMA w-GEMM + fp32 t-update; t written as split-bf16 frag planes tA
//   k_amfma    : OF[o,(k,b,m)] = sum_i a[o,i] tA[i,(k,b,m)]   (split-bf16 MFMA) -> OF fp32
//   k_ihinv    : FUSED per-bo block: phase1 Z[h][kw] = sum_k IH[h][k] OF[k][bo,kw]
//                (OF split on the fly, Z -> LDS bf16-hi, XOR-swizzled);
//                phase2 out[bo,h,w] = Re(Z . E) via MFMA from LDS.

#define TWO_PI 6.28318530717958647692f

typedef __attribute__((ext_vector_type(8))) short short8v;   // 8 bf16 (4 VGPRs)
typedef __attribute__((ext_vector_type(4))) float float4v;   // MFMA C/D

namespace {
constexpr size_t P_ = 32768;            // B*C*KW pixel batch width

// workspace float offsets
constexpr size_t oYT = 0;                     // Yt: 4 planes [32][32768][8] bf16 = 16.77M floats
                                              //   then bA/gB + tA (contract)
constexpr size_t oTA = 1048576;               // tA: 4 planes [8][32768][8] bf16
constexpr size_t oXF = 16777216;              // XF f2 33.5MB
constexpr size_t oOF = 25165824;              // OF f2 33.5MB (read by k_ihinv)
constexpr size_t oBF = 33554432;              // FW B-frag table: 65536 shorts
constexpr size_t oAF1 = 33587200;             // FH frags: 196608 shorts
constexpr size_t oAF2 = 33685504;             // IH frags
constexpr size_t oG  = 33792000;              // [2][32][64][64] f2 ; AFa (1st half) + EF (2nd half)
constexpr size_t oEF = oG + 262144;           // EF: 32768 shorts = 16384 floats
constexpr size_t WS_FLOATS = oG + 524288;     // ~137.3 MB
}

__device__ __forceinline__ unsigned short f2bf(float f) {   // RNE float->bf16 bits
    unsigned int u = __float_as_uint(f);
    unsigned int r = (u + 0x7FFFu + ((u >> 16) & 1u)) >> 16;
    return (unsigned short)r;
}
__device__ __forceinline__ float bf2f(unsigned short b) {
    return __uint_as_float(((unsigned int)b) << 16);
}

// Split-bf16 fragment tables for the DFT matrices (AF1 FH, AF2 IH, BF FW).
__global__ __launch_bounds__(256) void k_prepT(unsigned short* __restrict__ AF1,
                                               unsigned short* __restrict__ AF2,
                                               unsigned short* __restrict__ BF) {
    int idx = blockIdx.x * 256 + threadIdx.x;      // < 458752
    if (idx < 393216) {
        int tbl = (idx >= 196608);
        int id = tbl ? (idx - 196608) : idx;
        int e = id & 7, lane = (id >> 3) & 63;
        int pl = id >> 15;
        float ang;
        if (!tbl) {
            int rt = (id >> 9) & 7, kc = (id >> 12) & 7;
            int r = rt * 16 + (lane & 15);             // k-row (128)
            int s = kc * 32 + 8 * (lane >> 4) + e;     // h (256)
            int kh = r + ((r >= 64) ? 128 : 0);
            int ph = (kh * s) & 255;
            ang = -TWO_PI * (float)ph / 256.0f;
        } else {
            int rt = (id >> 9) & 15, kc = (id >> 13) & 3;
            int r = rt * 16 + (lane & 15);             // h (256)
            int s = kc * 32 + 8 * (lane >> 4) + e;     // k (128)
            int kh = s + ((s >= 64) ? 128 : 0);
            int ph = (kh * r) & 255;
            ang = TWO_PI * (float)ph / 256.0f;
        }
        float sn, cs; sincosf(ang, &sn, &cs);
        float base = (pl < 2) ? cs : ((pl < 4) ? sn : -sn);
        unsigned short hi = f2bf(base);
        unsigned short out = (pl & 1) ? f2bf(base - bf2f(hi)) : hi;
        (tbl ? AF2 : AF1)[id] = out;
    } else {
        int id = idx - 393216;                          // < 65536
        int e = id & 7, lane = (id >> 3) & 63;
        int nt = (id >> 9) & 3, kc = (id >> 11) & 7;
        int pl = id >> 14;                              // 0..3
        int kw = nt * 16 + (lane & 15);
        int w = kc * 32 + 8 * (lane >> 4) + e;
        int ph = (w * kw) & 255;
        float ang = -TWO_PI * (float)ph / 256.0f;
        float sn, cs; sincosf(ang, &sn, &cs);
        float base = (pl < 2) ? cs : sn;
        unsigned short hi = f2bf(base);
        unsigned short out = (pl & 1) ? f2bf(base - bf2f(hi)) : hi;
        BF[id] = out;
    }
}

// bf16-hi B-frag table for the inverse-W twiddle:
// EF[pl(2: Er, -Ei)][kc(2)][nt(16)][lane][e], E[kw][w] = s_kw/65536 * e^{+2pi i kw w/256}
__global__ __launch_bounds__(256) void k_prepE(unsigned short* __restrict__ EF) {
    int idx = blockIdx.x * 256 + threadIdx.x;      // < 32768
    int e = idx & 7, lane = (idx >> 3) & 63;
    int nt = (idx >> 9) & 15, kc = (idx >> 13) & 1, pl = idx >> 14;
    int w = nt * 16 + (lane & 15);
    int kw = kc * 32 + 8 * (lane >> 4) + e;
    int ph = (kw * w) & 255;
    float ang = TWO_PI * (float)ph / 256.0f;
    float sn, cs; sincosf(ang, &sn, &cs);
    float sc = ((kw == 0) ? 1.0f : 2.0f) / 65536.0f;
    float v = (pl == 0) ? (sc * cs) : (-sc * sn);
    EF[idx] = f2bf(v);
}

// g[r][j][x][y] = sum_k cc[j,x,k] * dc[k,y]
__global__ __launch_bounds__(256) void k_g(const float* __restrict__ c1, const float* __restrict__ d1,
                                           const float* __restrict__ c2, const float* __restrict__ d2,
                                           float2* __restrict__ G) {
    int idx = blockIdx.x * 256 + threadIdx.x;      // < 262144
    int r = idx >> 17;
    int rem = idx & 131071;
    int j = rem >> 12;
    int xy = rem & 4095;
    int xm = xy >> 6, ym = xy & 63;
    const float* cp = r ? c2 : c1;
    const float* dp = r ? d2 : d1;
    float sr = 0.f, si = 0.f;
    for (int kk = 0; kk < 32; ++kk) {
        float cr = cp[((j * 64 + xm) * 32 + kk) * 2 + 0];
        float ci = cp[((j * 64 + xm) * 32 + kk) * 2 + 1];
        float dr = dp[(kk * 64 + ym) * 2 + 0];
        float di = dp[(kk * 64 + ym) * 2 + 1];
        sr = fmaf(cr, dr, fmaf(-ci, di, sr));
        si = fmaf(cr, di, fmaf( ci, dr, si));
    }
    G[(size_t)(r * 32 + j) * 4096 + xy] = make_float2(sr, si);
}

// bf16 fragment tables for the contraction.
__global__ __launch_bounds__(256) void k_prepBG(const float* __restrict__ b1, const float* __restrict__ b2,
                                                const float2* __restrict__ G,
                                                unsigned short* __restrict__ bA,
                                                unsigned short* __restrict__ gB) {
    size_t idx = (size_t)blockIdx.x * 256 + threadIdx.x;
    if (idx < 1048576) {
        int e     = idx & 7;
        int lane  = (idx >> 3) & 63;
        int c     = (idx >> 9) & 127;
        int itile = (idx >> 16) & 3;
        int reg   = (idx >> 18) & 1;
        int plane = (idx >> 19) & 1;
        int i = itile * 16 + (lane & 15);
        int j = 8 * (lane >> 4) + e;
        const float* bp = reg ? b2 : b1;
        float v = bp[((size_t)(i * 128 + c) * 32 + j) * 2 + plane];
        bA[idx] = f2bf(v);
    } else if (idx < 1048576 + 786432) {
        size_t i2 = idx - 1048576;
        int e     = i2 & 7;
        int lane  = (i2 >> 3) & 63;
        int ytile = (i2 >> 9) & 3;
        int x     = (i2 >> 11) & 63;
        int reg   = (i2 >> 17) & 1;
        int plane = (int)(i2 >> 18);           // 0,1,2
        int y = ytile * 16 + (lane & 15);
        int j = 8 * (lane >> 4) + e;
        float2 gv = G[(size_t)(reg * 32 + j) * 4096 + x * 64 + y];
        float v = (plane == 0) ? gv.x : ((plane == 1) ? gv.y : -gv.y);
        gB[i2] = f2bf(v);
    }
}

// Split-bf16 A-frag table for the a-epilogue GEMM (M=o=128, K=i=64).
__global__ __launch_bounds__(256) void k_prepA(const float* __restrict__ a1, const float* __restrict__ a2,
                                               unsigned short* __restrict__ AFa) {
    int idx = blockIdx.x * 256 + threadIdx.x;      // < 98304
    int e = idx & 7, lane = (idx >> 3) & 63;
    int rt = (idx >> 9) & 7, kc = (idx >> 12) & 1;
    int plreg = idx >> 13;                          // 0..11
    int reg = plreg / 6, pl = plreg % 6;
    int o = rt * 16 + (lane & 15);
    int i = kc * 32 + 8 * (lane >> 4) + e;
    const float* ap = reg ? a2 : a1;
    float ar = ap[(o * 64 + i) * 2 + 0];
    float ai = ap[(o * 64 + i) * 2 + 1];
    float base = (pl < 2) ? ar : ((pl < 4) ? ai : -ai);
    unsigned short hi = f2bf(base);
    unsigned short out = (pl & 1) ? f2bf(base - bf2f(hi)) : hi;
    AFa[idx] = out;
}

// MFMA W-DFT v4: BF staged via LDS in 32KB barrier-synced phases (2 kc each).
__global__ __launch_bounds__(256) void k_stage1m(const float* __restrict__ x,
                                                 const unsigned short* __restrict__ BF,
                                                 unsigned short* __restrict__ Yt) {
    __shared__ __align__(16) unsigned short es[16384];   // 32 KB
    int t = threadIdx.x;
    int wave = t >> 6, lane = t & 63;
    size_t row0 = (size_t)blockIdx.x * 128 + (size_t)wave * 32;
    int colp = lane & 15, rowq = lane >> 4;
    const short8v* esv = (const short8v*)es;

    float4v accR[2][4], accI[2][4];
#pragma unroll
    for (int rt = 0; rt < 2; ++rt)
#pragma unroll
        for (int nt = 0; nt < 4; ++nt) {
            accR[rt][nt] = (float4v){0.f, 0.f, 0.f, 0.f};
            accI[rt][nt] = (float4v){0.f, 0.f, 0.f, 0.f};
        }

    const float* xb0 = x + (row0 + colp) * 256 + 8 * rowq;
    const float* xb1 = xb0 + 16 * 256;
    float4 nv[2][2];
    nv[0][0] = *(const float4*)(xb0);  nv[0][1] = *(const float4*)(xb0 + 4);
    nv[1][0] = *(const float4*)(xb1);  nv[1][1] = *(const float4*)(xb1 + 4);

    const float4* bf4 = (const float4*)BF;
    for (int ph = 0; ph < 4; ++ph) {
        __syncthreads();
        {
#pragma unroll
            for (int i = 0; i < 8; ++i) {
                int idx = t + 256 * i;
                int li  = idx & 63;
                int nt  = (idx >> 6) & 3;
                int kcl = (idx >> 8) & 1;
                int pl  = idx >> 9;
                ((float4*)es)[idx] = bf4[((size_t)(pl * 8 + ph * 2 + kcl) * 4 + nt) * 64 + li];
            }
        }
        __syncthreads();
        for (int kcl = 0; kcl < 2; ++kcl) {
            int kc = ph * 2 + kcl;
            short8v xh[2];
#pragma unroll
            for (int rt = 0; rt < 2; ++rt) {
                float4 v0 = nv[rt][0], v1 = nv[rt][1];
                float vv[8] = {v0.x, v0.y, v0.z, v0.w, v1.x, v1.y, v1.z, v1.w};
#pragma unroll
                for (int j = 0; j < 8; ++j) xh[rt][j] = (short)f2bf(vv[j]);
            }
            if (kc < 7) {
                nv[0][0] = *(const float4*)(xb0 + (kc + 1) * 32);
                nv[0][1] = *(const float4*)(xb0 + (kc + 1) * 32 + 4);
                nv[1][0] = *(const float4*)(xb1 + (kc + 1) * 32);
                nv[1][1] = *(const float4*)(xb1 + (kc + 1) * 32 + 4);
            }
#pragma unroll
            for (int nt = 0; nt < 4; ++nt) {
                short8v Bch = esv[((0 * 2 + kcl) * 4 + nt) * 64 + lane];
                short8v Bcl = esv[((1 * 2 + kcl) * 4 + nt) * 64 + lane];
                short8v Bsh = esv[((2 * 2 + kcl) * 4 + nt) * 64 + lane];
                short8v Bsl = esv[((3 * 2 + kcl) * 4 + nt) * 64 + lane];
#pragma unroll
                for (int rt = 0; rt < 2; ++rt) {
                    float4v r_ = accR[rt][nt];
                    r_ = __builtin_amdgcn_mfma_f32_16x16x32_bf16(xh[rt], Bch, r_, 0, 0, 0);
                    r_ = __builtin_amdgcn_mfma_f32_16x16x32_bf16(xh[rt], Bcl, r_, 0, 0, 0);
                    accR[rt][nt] = r_;
                    float4v i_ = accI[rt][nt];
                    i_ = __builtin_amdgcn_mfma_f32_16x16x32_bf16(xh[rt], Bsh, i_, 0, 0, 0);
                    i_ = __builtin_amdgcn_mfma_f32_16x16x32_bf16(xh[rt], Bsl, i_, 0, 0, 0);
                    accI[rt][nt] = i_;
                }
            }
        }
    }

    short* Yts = (short*)Yt;
    const size_t PLY = (size_t)32 * 32768 * 8;
#pragma unroll
    for (int rt = 0; rt < 2; ++rt) {
        size_t xrow0 = row0 + rt * 16 + rowq * 4;
        int h = (int)(xrow0 & 255), bc = (int)(xrow0 >> 8);
        size_t gbase = (size_t)(h >> 3) * 32768;
        int e0 = h & 7;
#pragma unroll
        for (int nt = 0; nt < 4; ++nt) {
            size_t p = (size_t)bc * 64 + nt * 16 + colp;
            size_t off = (gbase + p) * 8 + e0;
            float4v R = accR[rt][nt], I = accI[rt][nt];
            short rh[4], rl[4], ih[4], il[4];
#pragma unroll
            for (int q = 0; q < 4; ++q) {
                unsigned short h1 = f2bf(R[q]);
                rh[q] = (short)h1; rl[q] = (short)f2bf(R[q] - bf2f(h1));
                unsigned short h2 = f2bf(I[q]);
                ih[q] = (short)h2; il[q] = (short)f2bf(I[q] - bf2f(h2));
            }
            *(short4*)&Yts[0 * PLY + off] = make_short4(rh[0], rh[1], rh[2], rh[3]);
            *(short4*)&Yts[1 * PLY + off] = make_short4(rl[0], rl[1], rl[2], rl[3]);
            *(short4*)&Yts[2 * PLY + off] = make_short4(ih[0], ih[1], ih[2], ih[3]);
            *(short4*)&Yts[3 * PLY + off] = make_short4(il[0], il[1], il[2], il[3]);
        }
    }
}

// Split-bf16 complex MFMA GEMM (used for FH: Yt -> XF).
template<int S, int RT_W>
__global__ __launch_bounds__(256) void k_cmfma(const unsigned short* __restrict__ AF,
                                               const unsigned short* __restrict__ Bt,
                                               float2* __restrict__ Out) {
    constexpr int KC = S / 32;
    constexpr int SG = S / 8;
    constexpr int RTOT = RT_W * 4;
    __shared__ __align__(16) unsigned short bs[4 * SG * 16 * 8];
    int t = threadIdx.x;
    int wave = t >> 6, lane = t & 63;
    int rt0 = wave * RT_W;
    int colp = lane & 15, rowq = lane >> 4;
    const short8v* AFv = (const short8v*)AF;
    const short8v* bsv = (const short8v*)bs;
    const size_t PLA = (size_t)KC * RTOT * 64;

    for (int pt = 0; pt < 4; ++pt) {
        int p0 = blockIdx.x * 64 + pt * 16;
        __syncthreads();
        {
            const float4* src = (const float4*)Bt;
            float4* dst = (float4*)bs;
            for (int e = t; e < 4 * SG * 16; e += 256) {
                int pl = e / (SG * 16); int rem = e - pl * (SG * 16);
                int g = rem >> 4, li = rem & 15;
                dst[e] = src[((size_t)pl * SG + g) * 32768 + p0 + li];
            }
        }
        __syncthreads();
        float4v accR[RT_W], accI[RT_W];
#pragma unroll
        for (int rt = 0; rt < RT_W; ++rt) {
            accR[rt] = (float4v){0.f, 0.f, 0.f, 0.f};
            accI[rt] = (float4v){0.f, 0.f, 0.f, 0.f};
        }
#pragma unroll
        for (int kc = 0; kc < KC; ++kc) {
            int gi = kc * 4 + rowq;
            short8v Brh = bsv[((0 * SG + gi) << 4) + colp];
            short8v Brl = bsv[((1 * SG + gi) << 4) + colp];
            short8v Bih = bsv[((2 * SG + gi) << 4) + colp];
            short8v Bil = bsv[((3 * SG + gi) << 4) + colp];
#pragma unroll
            for (int rt = 0; rt < RT_W; ++rt) {
                size_t ab = ((size_t)kc * RTOT + rt0 + rt) * 64 + lane;
                short8v A0 = AFv[0 * PLA + ab];
                short8v A1 = AFv[1 * PLA + ab];
                short8v A2 = AFv[2 * PLA + ab];
                short8v A3 = AFv[3 * PLA + ab];
                short8v A4 = AFv[4 * PLA + ab];
                short8v A5 = AFv[5 * PLA + ab];
                float4v r_ = accR[rt];
                r_ = __builtin_amdgcn_mfma_f32_16x16x32_bf16(A0, Brh, r_, 0, 0, 0);
                r_ = __builtin_amdgcn_mfma_f32_16x16x32_bf16(A0, Brl, r_, 0, 0, 0);
                r_ = __builtin_amdgcn_mfma_f32_16x16x32_bf16(A1, Brh, r_, 0, 0, 0);
                r_ = __builtin_amdgcn_mfma_f32_16x16x32_bf16(A4, Bih, r_, 0, 0, 0);
                r_ = __builtin_amdgcn_mfma_f32_16x16x32_bf16(A4, Bil, r_, 0, 0, 0);
                r_ = __builtin_amdgcn_mfma_f32_16x16x32_bf16(A5, Bih, r_, 0, 0, 0);
                accR[rt] = r_;
                float4v i_ = accI[rt];
                i_ = __builtin_amdgcn_mfma_f32_16x16x32_bf16(A2, Brh, i_, 0, 0, 0);
                i_ = __builtin_amdgcn_mfma_f32_16x16x32_bf16(A2, Brl, i_, 0, 0, 0);
                i_ = __builtin_amdgcn_mfma_f32_16x16x32_bf16(A3, Brh, i_, 0, 0, 0);
                i_ = __builtin_amdgcn_mfma_f32_16x16x32_bf16(A0, Bih, i_, 0, 0, 0);
                i_ = __builtin_amdgcn_mfma_f32_16x16x32_bf16(A0, Bil, i_, 0, 0, 0);
                i_ = __builtin_amdgcn_mfma_f32_16x16x32_bf16(A1, Bih, i_, 0, 0, 0);
                accI[rt] = i_;
            }
        }
#pragma unroll
        for (int rt = 0; rt < RT_W; ++rt) {
            int rbase = (rt0 + rt) * 16 + rowq * 4;
#pragma unroll
            for (int q = 0; q < 4; ++q)
                Out[(size_t)(rbase + q) * P_ + p0 + colp] = make_float2(accR[rt][q], accI[rt][q]);
        }
    }
}

// MFMA contract, phase A.
__global__ __launch_bounds__(256) void k_contractA(const float2* __restrict__ XF,
                                                   const unsigned short* __restrict__ bA,
                                                   const unsigned short* __restrict__ gB,
                                                   unsigned short* __restrict__ tA) {
    int t = threadIdx.x;
    int k = blockIdx.x >> 2;
    int ytile = blockIdx.x & 3;
    int y0 = ytile << 4;
    int reg = (k >= 64) ? 1 : 0;
    int x = k & 63;
    int itile = t >> 6, lane = t & 63;
    int ylane = lane & 15, qg = lane >> 4;

    const short8v* gBv = (const short8v*)gB;
    short8v g_r  = gBv[(((size_t)(0 * 2 + reg) * 64 + x) * 4 + ytile) * 64 + lane];
    short8v g_i  = gBv[(((size_t)(1 * 2 + reg) * 64 + x) * 4 + ytile) * 64 + lane];
    short8v g_ni = gBv[(((size_t)(2 * 2 + reg) * 64 + x) * 4 + ytile) * 64 + lane];

    const short8v* bAv = (const short8v*)bA;
    size_t aR = (((size_t)(0 * 2 + reg) * 4 + itile) * 128) * 64 + lane;
    size_t aI = (((size_t)(1 * 2 + reg) * 4 + itile) * 128) * 64 + lane;

    const float2* xfp = XF + (size_t)k * 32768 + y0 + ylane;

    float tr[4][4], ti[4][4];
#pragma unroll
    for (int q = 0; q < 4; ++q)
#pragma unroll
        for (int b = 0; b < 4; ++b) { tr[q][b] = 0.f; ti[q][b] = 0.f; }

#pragma unroll 2
    for (int c = 0; c < 128; ++c) {
        short8v av = bAv[aR + (size_t)c * 64];
        short8v aw = bAv[aI + (size_t)c * 64];
        float4v z4 = {0.f, 0.f, 0.f, 0.f};
        float4v wr = __builtin_amdgcn_mfma_f32_16x16x32_bf16(av, g_r, z4, 0, 0, 0);
        wr = __builtin_amdgcn_mfma_f32_16x16x32_bf16(aw, g_ni, wr, 0, 0, 0);
        float4v wi = __builtin_amdgcn_mfma_f32_16x16x32_bf16(av, g_i, z4, 0, 0, 0);
        wi = __builtin_amdgcn_mfma_f32_16x16x32_bf16(aw, g_r, wi, 0, 0, 0);
#pragma unroll
        for (int b = 0; b < 4; ++b) {
            float2 xv = xfp[(size_t)b * 8192 + (size_t)c * 64];
#pragma unroll
            for (int q = 0; q < 4; ++q) {
                tr[q][b] = fmaf(wr[q], xv.x, fmaf(-wi[q], xv.y, tr[q][b]));
                ti[q][b] = fmaf(wr[q], xv.y, fmaf( wi[q], xv.x, ti[q][b]));
            }
        }
    }

    short* tAs = (short*)tA;
    const size_t PLT = (size_t)8 * 32768 * 8;
    int gidx = itile * 2 + (qg >> 1);
    int e0 = (qg & 1) * 4;
#pragma unroll
    for (int b = 0; b < 4; ++b) {
        size_t col = (size_t)k * 256 + (size_t)b * 64 + y0 + ylane;
        size_t off = ((size_t)gidx * 32768 + col) * 8 + e0;
        short rh[4], rl[4], ih[4], il[4];
#pragma unroll
        for (int q = 0; q < 4; ++q) {
            unsigned short h1 = f2bf(tr[q][b]);
            rh[q] = (short)h1; rl[q] = (short)f2bf(tr[q][b] - bf2f(h1));
            unsigned short h2 = f2bf(ti[q][b]);
            ih[q] = (short)h2; il[q] = (short)f2bf(ti[q][b] - bf2f(h2));
        }
        *(short4*)&tAs[0 * PLT + off] = make_short4(rh[0], rh[1], rh[2], rh[3]);
        *(short4*)&tAs[1 * PLT + off] = make_short4(rl[0], rl[1], rl[2], rl[3]);
        *(short4*)&tAs[2 * PLT + off] = make_short4(ih[0], ih[1], ih[2], ih[3]);
        *(short4*)&tAs[3 * PLT + off] = make_short4(il[0], il[1], il[2], il[3]);
    }
}

// MFMA contract, phase B -> OF fp32.
__global__ __launch_bounds__(256) void k_amfma(const unsigned short* __restrict__ AFa,
                                               const unsigned short* __restrict__ tA,
                                               float2* __restrict__ OF) {
    constexpr int SG = 8;
    __shared__ __align__(16) unsigned short bs[4 * SG * 16 * 8];
    int t = threadIdx.x;
    int wave = t >> 6, lane = t & 63;
    int rt0 = wave * 2;
    int colp = lane & 15, rowq = lane >> 4;
    int k = blockIdx.x >> 2, b = blockIdx.x & 3;
    int reg = (k >= 64) ? 1 : 0;
    const short8v* AFv = (const short8v*)(AFa + (size_t)reg * 6 * 2 * 8 * 512);
    const size_t PLA = 2 * 8 * 64;
    const short8v* bsv = (const short8v*)bs;
    size_t p0 = (size_t)blockIdx.x * 64;

    for (int pt = 0; pt < 4; ++pt) {
        __syncthreads();
        {
            const float4* src = (const float4*)tA;
            float4* dst = (float4*)bs;
            for (int e = t; e < 4 * SG * 16; e += 256) {
                int pl = e >> 7; int rem = e & 127;
                int g = rem >> 4, li = rem & 15;
                dst[e] = src[((size_t)pl * SG + g) * 32768 + p0 + pt * 16 + li];
            }
        }
        __syncthreads();
        float4v accR[2], accI[2];
#pragma unroll
        for (int rt = 0; rt < 2; ++rt) {
            accR[rt] = (float4v){0.f, 0.f, 0.f, 0.f};
            accI[rt] = (float4v){0.f, 0.f, 0.f, 0.f};
        }
#pragma unroll
        for (int kc = 0; kc < 2; ++kc) {
            int gi = kc * 4 + rowq;
            short8v Brh = bsv[((0 * SG + gi) << 4) + colp];
            short8v Brl = bsv[((1 * SG + gi) << 4) + colp];
            short8v Bih = bsv[((2 * SG + gi) << 4) + colp];
            short8v Bil = bsv[((3 * SG + gi) << 4) + colp];
#pragma unroll
            for (int rt = 0; rt < 2; ++rt) {
                size_t ab = ((size_t)kc * 8 + rt0 + rt) * 64 + lane;
                short8v A0 = AFv[0 * PLA + ab];
                short8v A1 = AFv[1 * PLA + ab];
                short8v A2 = AFv[2 * PLA + ab];
                short8v A3 = AFv[3 * PLA + ab];
                short8v A4 = AFv[4 * PLA + ab];
                short8v A5 = AFv[5 * PLA + ab];
                float4v r_ = accR[rt];
                r_ = __builtin_amdgcn_mfma_f32_16x16x32_bf16(A0, Brh, r_, 0, 0, 0);
                r_ = __builtin_amdgcn_mfma_f32_16x16x32_bf16(A0, Brl, r_, 0, 0, 0);
                r_ = __builtin_amdgcn_mfma_f32_16x16x32_bf16(A1, Brh, r_, 0, 0, 0);
                r_ = __builtin_amdgcn_mfma_f32_16x16x32_bf16(A4, Bih, r_, 0, 0, 0);
                r_ = __builtin_amdgcn_mfma_f32_16x16x32_bf16(A4, Bil, r_, 0, 0, 0);
                r_ = __builtin_amdgcn_mfma_f32_16x16x32_bf16(A5, Bih, r_, 0, 0, 0);
                accR[rt] = r_;
                float4v i_ = accI[rt];
                i_ = __builtin_amdgcn_mfma_f32_16x16x32_bf16(A2, Brh, i_, 0, 0, 0);
                i_ = __builtin_amdgcn_mfma_f32_16x16x32_bf16(A2, Brl, i_, 0, 0, 0);
                i_ = __builtin_amdgcn_mfma_f32_16x16x32_bf16(A3, Brh, i_, 0, 0, 0);
                i_ = __builtin_amdgcn_mfma_f32_16x16x32_bf16(A0, Bih, i_, 0, 0, 0);
                i_ = __builtin_amdgcn_mfma_f32_16x16x32_bf16(A0, Bil, i_, 0, 0, 0);
                i_ = __builtin_amdgcn_mfma_f32_16x16x32_bf16(A1, Bih, i_, 0, 0, 0);
                accI[rt] = i_;
            }
        }
        int m = pt * 16 + colp;
#pragma unroll
        for (int rt = 0; rt < 2; ++rt) {
            int o0 = (rt0 + rt) * 16 + rowq * 4;
#pragma unroll
            for (int q = 0; q < 4; ++q)
                OF[(size_t)k * 32768 + (size_t)b * 8192 + (size_t)(o0 + q) * 64 + m] =
                    make_float2(accR[rt][q], accI[rt][q]);
        }
    }
}

// FUSED IH-GEMM + inverse-W MFMA. Block = one bo (b*128+o), 512 threads (8 waves).
// Phase 1: Z[h][kw] = sum_k IH[h][k] * OF[k][p0+kw]; OF split hi/lo on the fly;
//          Z stored bf16-hi in LDS, XOR-swizzled (kw ^ ((h&7)<<3)).
// Phase 2: out[bo,h,w] = Re(Z . E), A-frags from LDS, EF B-frags from L2.
__global__ __launch_bounds__(512) void k_ihinv(const unsigned short* __restrict__ AF2,
                                               const float2* __restrict__ OF,
                                               const unsigned short* __restrict__ EF,
                                               float* __restrict__ out) {
    constexpr int SG = 16, KC = 4, RTOT = 16;
    __shared__ __align__(16) unsigned short zs[2 * 256 * 64];     // 64 KB: [pl][h][kw^((h&7)<<3)]
    __shared__ __align__(16) unsigned short bs[4 * SG * 16 * 8];  // 16 KB
    int t = threadIdx.x;
    int wave = t >> 6, lane = t & 63;
    int colp = lane & 15, rowq = lane >> 4;
    int rt0 = wave * 2;
    int bo = blockIdx.x;
    size_t p0 = (size_t)bo * 64;
    const short8v* AFv = (const short8v*)AF2;
    const short8v* bsv = (const short8v*)bs;
    const size_t PLA = (size_t)KC * RTOT * 64;

    for (int pt = 0; pt < 4; ++pt) {
        __syncthreads();
        {   // stage B tile from OF fp32 (split hi/lo): 512 threads x 4 rows each
            int li = t & 15, g = (t >> 4) & 15, half = t >> 8;
            int e0 = half * 4;
            short rh[4], rl[4], ih[4], il[4];
#pragma unroll
            for (int j = 0; j < 4; ++j) {
                float2 v = OF[(size_t)(g * 8 + e0 + j) * P_ + p0 + pt * 16 + li];
                unsigned short h1 = f2bf(v.x);
                rh[j] = (short)h1; rl[j] = (short)f2bf(v.x - bf2f(h1));
                unsigned short h2 = f2bf(v.y);
                ih[j] = (short)h2; il[j] = (short)f2bf(v.y - bf2f(h2));
            }
            int base = (g * 16 + li) * 8 + e0;
            *(short4*)&bs[0 * 2048 + base] = make_short4(rh[0], rh[1], rh[2], rh[3]);
            *(short4*)&bs[1 * 2048 + base] = make_short4(rl[0], rl[1], rl[2], rl[3]);
            *(short4*)&bs[2 * 2048 + base] = make_short4(ih[0], ih[1], ih[2], ih[3]);
            *(short4*)&bs[3 * 2048 + base] = make_short4(il[0], il[1], il[2], il[3]);
        }
        __syncthreads();
        float4v accR[2], accI[2];
#pragma unroll
        for (int rt = 0; rt < 2; ++rt) {
            accR[rt] = (float4v){0.f, 0.f, 0.f, 0.f};
            accI[rt] = (float4v){0.f, 0.f, 0.f, 0.f};
        }
#pragma unroll
        for (int kc = 0; kc < KC; ++kc) {
            int gi = kc * 4 + rowq;
            short8v Brh = bsv[((0 * SG + gi) << 4) + colp];
            short8v Brl = bsv[((1 * SG + gi) << 4) + colp];
            short8v Bih = bsv[((2 * SG + gi) << 4) + colp];
            short8v Bil = bsv[((3 * SG + gi) << 4) + colp];
#pragma unroll
            for (int rt = 0; rt < 2; ++rt) {
                size_t ab = ((size_t)kc * RTOT + rt0 + rt) * 64 + lane;
                short8v A0 = AFv[0 * PLA + ab];
                short8v A1 = AFv[1 * PLA + ab];
                short8v A2 = AFv[2 * PLA + ab];
                short8v A3 = AFv[3 * PLA + ab];
                short8v A4 = AFv[4 * PLA + ab];
                short8v A5 = AFv[5 * PLA + ab];
                float4v r_ = accR[rt];
                r_ = __builtin_amdgcn_mfma_f32_16x16x32_bf16(A0, Brh, r_, 0, 0, 0);
                r_ = __builtin_amdgcn_mfma_f32_16x16x32_bf16(A0, Brl, r_, 0, 0, 0);
                r_ = __builtin_amdgcn_mfma_f32_16x16x32_bf16(A1, Brh, r_, 0, 0, 0);
                r_ = __builtin_amdgcn_mfma_f32_16x16x32_bf16(A4, Bih, r_, 0, 0, 0);
                r_ = __builtin_amdgcn_mfma_f32_16x16x32_bf16(A4, Bil, r_, 0, 0, 0);
                r_ = __builtin_amdgcn_mfma_f32_16x16x32_bf16(A5, Bih, r_, 0, 0, 0);
                accR[rt] = r_;
                float4v i_ = accI[rt];
                i_ = __builtin_amdgcn_mfma_f32_16x16x32_bf16(A2, Brh, i_, 0, 0, 0);
                i_ = __builtin_amdgcn_mfma_f32_16x16x32_bf16(A2, Brl, i_, 0, 0, 0);
                i_ = __builtin_amdgcn_mfma_f32_16x16x32_bf16(A3, Brh, i_, 0, 0, 0);
                i_ = __builtin_amdgcn_mfma_f32_16x16x32_bf16(A0, Bih, i_, 0, 0, 0);
                i_ = __builtin_amdgcn_mfma_f32_16x16x32_bf16(A0, Bil, i_, 0, 0, 0);
                i_ = __builtin_amdgcn_mfma_f32_16x16x32_bf16(A1, Bih, i_, 0, 0, 0);
                accI[rt] = i_;
            }
        }
        // write Z (bf16-hi) to LDS, swizzled
#pragma unroll
        for (int rt = 0; rt < 2; ++rt)
#pragma unroll
            for (int q = 0; q < 4; ++q) {
                int h = (rt0 + rt) * 16 + rowq * 4 + q;
                int kwsw = (pt * 16 + colp) ^ ((h & 7) << 3);
                zs[h * 64 + kwsw] = (unsigned short)f2bf(accR[rt][q]);
                zs[16384 + h * 64 + kwsw] = (unsigned short)f2bf(accI[rt][q]);
            }
    }
    __syncthreads();

    // Phase 2: out rows = h (8 waves x 2 mtiles x 16), cols = w (16 nt x 16).
    const short8v* EFv = (const short8v*)EF;
    for (int nt = 0; nt < 16; ++nt) {
        short8v Er0  = EFv[((0 * 2 + 0) * 16 + nt) * 64 + lane];
        short8v Er1  = EFv[((0 * 2 + 1) * 16 + nt) * 64 + lane];
        short8v nEi0 = EFv[((1 * 2 + 0) * 16 + nt) * 64 + lane];
        short8v nEi1 = EFv[((1 * 2 + 1) * 16 + nt) * 64 + lane];
#pragma unroll
        for (int mtl = 0; mtl < 2; ++mtl) {
            int h0 = (wave * 2 + mtl) * 16;
            int hA = h0 + colp;
            int sw = (hA & 7) << 3;
            short8v Zr0 = *(const short8v*)&zs[hA * 64 + ((8 * rowq) ^ sw)];
            short8v Zr1 = *(const short8v*)&zs[hA * 64 + ((32 + 8 * rowq) ^ sw)];
            short8v Zi0 = *(const short8v*)&zs[16384 + hA * 64 + ((8 * rowq) ^ sw)];
            short8v Zi1 = *(const short8v*)&zs[16384 + hA * 64 + ((32 + 8 * rowq) ^ sw)];
            float4v acc = {0.f, 0.f, 0.f, 0.f};
            acc = __builtin_amdgcn_mfma_f32_16x16x32_bf16(Zr0, Er0,  acc, 0, 0, 0);
            acc = __builtin_amdgcn_mfma_f32_16x16x32_bf16(Zi0, nEi0, acc, 0, 0, 0);
            acc = __builtin_amdgcn_mfma_f32_16x16x32_bf16(Zr1, Er1,  acc, 0, 0, 0);
            acc = __builtin_amdgcn_mfma_f32_16x16x32_bf16(Zi1, nEi1, acc, 0, 0, 0);
            size_t ob = ((size_t)bo * 256 + h0 + rowq * 4) * 256 + nt * 16 + colp;
#pragma unroll
            for (int q = 0; q < 4; ++q)
                out[ob + (size_t)q * 256] = acc[q];
        }
    }
}

extern "C" void kernel_launch(void* const* d_in, const int* in_sizes, int n_in,
                              void* d_out, int out_size, void* d_ws, size_t ws_size,
                              hipStream_t stream) {
    const float* x  = (const float*)d_in[0];
    const float* a1 = (const float*)d_in[1];
    const float* b1 = (const float*)d_in[2];
    const float* c1 = (const float*)d_in[3];
    const float* d1 = (const float*)d_in[4];
    const float* a2 = (const float*)d_in[5];
    const float* b2 = (const float*)d_in[6];
    const float* c2 = (const float*)d_in[7];
    const float* d2 = (const float*)d_in[8];
    float* out = (float*)d_out;
    float* wsf = (float*)d_ws;

    if (ws_size < WS_FLOATS * sizeof(float)) return;

    unsigned short* Yt  = (unsigned short*)(wsf + oYT);
    float2*         XF  = (float2*)(wsf + oXF);
    float2*         OF  = (float2*)(wsf + oOF);
    float2*         G   = (float2*)(wsf + oG);
    unsigned short* BF  = (unsigned short*)(wsf + oBF);
    unsigned short* AF1 = (unsigned short*)(wsf + oAF1);
    unsigned short* AF2 = (unsigned short*)(wsf + oAF2);
    unsigned short* bA  = (unsigned short*)(wsf + oYT);  // after cmfma1, Yt region is dead
    unsigned short* gB  = bA + 1048576;
    unsigned short* tA  = (unsigned short*)(wsf + oTA);
    unsigned short* AFa = (unsigned short*)(wsf + oG);   // overwrites G (1st half) after prepBG
    unsigned short* EF  = (unsigned short*)(wsf + oEF);  // G 2nd half, after prepBG

    k_prepT<<<1792, 256, 0, stream>>>(AF1, AF2, BF);
    k_g<<<1024, 256, 0, stream>>>(c1, d1, c2, d2, G);
    k_stage1m<<<1024, 256, 0, stream>>>(x, BF, Yt);
    k_cmfma<256, 2><<<512, 256, 0, stream>>>(AF1, Yt, XF);
    k_prepBG<<<7168, 256, 0, stream>>>(b1, b2, G, bA, gB);
    k_prepA<<<384, 256, 0, stream>>>(a1, a2, AFa);       // G dead after prepBG
    k_prepE<<<128, 256, 0, stream>>>(EF);                // G 2nd half
    k_contractA<<<512, 256, 0, stream>>>(XF, bA, gB, tA);
    k_amfma<<<512, 256, 0, stream>>>(AFa, tA, OF);
    k_ihinv<<<512, 512, 0, stream>>>(AF2, OF, EF, out);

    (void)in_sizes; (void)n_in; (void)out_size;
}